// Round 5
// baseline (444.021 us; speedup 1.0000x reference)
//
#include <hip/hip_runtime.h>

// EPCOR eval path on MI355X — MFMA recompute version (no pd materialization).
// pd regenerated per pass from fp32->3xbf16 split operands (6-term MFMA).
// Row-argmax (the only exact-sensitive decision) is refined in exact fp32
// via a top-2 candidate rescue (fix_k).
#define BB 8
#define CC 64
#define NN 2048
#define MM 2048
#define KSEL 613            // 0-based index of the 614-th smallest (int(2048*0.3)=614)

// Output layout (floats): src_corr [B,3,N] | src_weight [B,N] | mask_src [B,N] | mask_tgt [B,M]
#define OUT_W  (BB * 3 * NN)
#define OUT_MS (OUT_W + BB * NN)
#define OUT_MT (OUT_MS + BB * NN)

typedef __attribute__((ext_vector_type(8))) short v8s;
typedef __attribute__((ext_vector_type(4))) float v4f;

static __device__ inline unsigned short f2bf(float x) {
    union { float f; unsigned u; } v; v.f = x;
    unsigned r = v.u + 0x7FFF + ((v.u >> 16) & 1);   // round-to-nearest-even
    return (unsigned short)(r >> 16);
}
static __device__ inline float bf2f(unsigned short h) {
    union { float f; unsigned u; } v; v.u = ((unsigned)h) << 16; return v.f;
}

// ---------- K0: split fp32 [B,64,L] -> 3x bf16 transposed [B,L,64] + sq-norms ----------
__global__ __launch_bounds__(256) void split_k(const float* __restrict__ in,
                                               unsigned short* __restrict__ T0,
                                               unsigned short* __restrict__ T1,
                                               unsigned short* __restrict__ T2,
                                               float* __restrict__ nrm) {
    __shared__ float tile[64][64];  // [c][n]
    __shared__ float xs[64][4];
    int b = blockIdx.y;
    int n0 = blockIdx.x << 6;
    int t = threadIdx.x;
    int c4 = t >> 6, nl = t & 63;
#pragma unroll
    for (int r = 0; r < 16; ++r) {
        int c = (r << 2) + c4;
        tile[c][nl] = in[((size_t)(b * CC + c)) * NN + n0 + nl];
    }
    __syncthreads();
    int n = t >> 2, cq = t & 3;
    size_t base = ((size_t)(b * NN + n0 + n)) * 64 + cq * 16;
    float ss = 0.f;
#pragma unroll
    for (int j = 0; j < 16; ++j) {
        float a = tile[cq * 16 + j][n];
        ss += a * a;
        unsigned short h0 = f2bf(a);
        float r1 = a - bf2f(h0);
        unsigned short h1 = f2bf(r1);
        float r2 = r1 - bf2f(h1);
        unsigned short h2 = f2bf(r2);
        T0[base + j] = h0; T1[base + j] = h1; T2[base + j] = h2;
    }
    xs[n][cq] = ss;
    __syncthreads();
    if (t < 64) nrm[b * NN + n0 + t] = xs[t][0] + xs[t][1] + xs[t][2] + xs[t][3];
}

// ---------- shared mainloop: 64x64 wave tile, 6-term bf16 MFMA, K=64 ----------
__device__ inline void gemm_main(const unsigned short* __restrict__ A0,
                                 const unsigned short* __restrict__ A1,
                                 const unsigned short* __restrict__ A2,
                                 const unsigned short* __restrict__ B0,
                                 const unsigned short* __restrict__ B1,
                                 const unsigned short* __restrict__ B2,
                                 int bB, int n0, int m0, int l15, int quad,
                                 v4f acc[4][4]) {
#pragma unroll
    for (int ks = 0; ks < 2; ++ks) {
        size_t ko = ks * 32 + quad * 8;
        size_t ra[4], rb[4];
#pragma unroll
        for (int q = 0; q < 4; ++q) {
            ra[q] = ((size_t)(bB + n0 + q * 16 + l15)) * 64 + ko;
            rb[q] = ((size_t)(bB + m0 + q * 16 + l15)) * 64 + ko;
        }
        v8s a0f[4], a1f[4], a2f[4], b0f[4], b1f[4], b2f[4];
#pragma unroll
        for (int q = 0; q < 4; ++q) { a0f[q] = *(const v8s*)(A0 + ra[q]); b0f[q] = *(const v8s*)(B0 + rb[q]); }
#pragma unroll
        for (int nt = 0; nt < 4; ++nt)
#pragma unroll
            for (int mt = 0; mt < 4; ++mt)
                acc[nt][mt] = __builtin_amdgcn_mfma_f32_16x16x32_bf16(a0f[nt], b0f[mt], acc[nt][mt], 0, 0, 0);
#pragma unroll
        for (int q = 0; q < 4; ++q) b1f[q] = *(const v8s*)(B1 + rb[q]);
#pragma unroll
        for (int nt = 0; nt < 4; ++nt)
#pragma unroll
            for (int mt = 0; mt < 4; ++mt)
                acc[nt][mt] = __builtin_amdgcn_mfma_f32_16x16x32_bf16(a0f[nt], b1f[mt], acc[nt][mt], 0, 0, 0);
#pragma unroll
        for (int q = 0; q < 4; ++q) b2f[q] = *(const v8s*)(B2 + rb[q]);
#pragma unroll
        for (int nt = 0; nt < 4; ++nt)
#pragma unroll
            for (int mt = 0; mt < 4; ++mt)
                acc[nt][mt] = __builtin_amdgcn_mfma_f32_16x16x32_bf16(a0f[nt], b2f[mt], acc[nt][mt], 0, 0, 0);
#pragma unroll
        for (int q = 0; q < 4; ++q) a1f[q] = *(const v8s*)(A1 + ra[q]);
#pragma unroll
        for (int nt = 0; nt < 4; ++nt)
#pragma unroll
            for (int mt = 0; mt < 4; ++mt)
                acc[nt][mt] = __builtin_amdgcn_mfma_f32_16x16x32_bf16(a1f[nt], b0f[mt], acc[nt][mt], 0, 0, 0);
#pragma unroll
        for (int nt = 0; nt < 4; ++nt)
#pragma unroll
            for (int mt = 0; mt < 4; ++mt)
                acc[nt][mt] = __builtin_amdgcn_mfma_f32_16x16x32_bf16(a1f[nt], b1f[mt], acc[nt][mt], 0, 0, 0);
#pragma unroll
        for (int q = 0; q < 4; ++q) a2f[q] = *(const v8s*)(A2 + ra[q]);
#pragma unroll
        for (int nt = 0; nt < 4; ++nt)
#pragma unroll
            for (int mt = 0; mt < 4; ++mt)
                acc[nt][mt] = __builtin_amdgcn_mfma_f32_16x16x32_bf16(a2f[nt], b0f[mt], acc[nt][mt], 0, 0, 0);
    }
}

#define WAVE_IDS \
    int t = threadIdx.x; int lane = t & 63; int wave = t >> 6; \
    int wx = wave & 1, wy = wave >> 1; \
    int l15 = lane & 15, quad = lane >> 4; \
    int b = blockIdx.z; int bB = b * NN; \
    int n0 = blockIdx.y * 128 + wy * 64; \
    int m0 = blockIdx.x * 128 + wx * 64;

// ---------- P1: row stats (top-2 value/index, sumexp) + col stats partials ----------
__global__ __launch_bounds__(256, 2) void pass1_k(const unsigned short* __restrict__ A0,
                                                  const unsigned short* __restrict__ A1,
                                                  const unsigned short* __restrict__ A2,
                                                  const unsigned short* __restrict__ B0,
                                                  const unsigned short* __restrict__ B1,
                                                  const unsigned short* __restrict__ B2,
                                                  const float* __restrict__ xx,
                                                  const float* __restrict__ yy,
                                                  float* __restrict__ rpM, float* __restrict__ rpS,
                                                  int* __restrict__ rpI,
                                                  float* __restrict__ rpM2, int* __restrict__ rpI2,
                                                  float* __restrict__ cpM, float* __restrict__ cpS) {
    WAVE_IDS
    v4f acc[4][4];
#pragma unroll
    for (int i = 0; i < 4; ++i)
#pragma unroll
        for (int j = 0; j < 4; ++j) acc[i][j] = (v4f){0.f, 0.f, 0.f, 0.f};
    gemm_main(A0, A1, A2, B0, B1, B2, bB, n0, m0, l15, quad, acc);
    float xv[4][4], yv[4];
#pragma unroll
    for (int nt = 0; nt < 4; ++nt)
#pragma unroll
        for (int r = 0; r < 4; ++r) xv[nt][r] = xx[bB + n0 + nt * 16 + quad * 4 + r];
#pragma unroll
    for (int mt = 0; mt < 4; ++mt) yv[mt] = yy[bB + m0 + mt * 16 + l15];
    // row stats with top-2 tracking
#pragma unroll
    for (int nt = 0; nt < 4; ++nt)
#pragma unroll
        for (int r = 0; r < 4; ++r) {
            float p[4];
#pragma unroll
            for (int mt = 0; mt < 4; ++mt) p[mt] = 2.f * acc[nt][mt][r] - xv[nt][r] - yv[mt];
            float v1 = p[0]; int i1 = m0 + l15;
            float v2 = -3.4e38f; int i2 = -1;
#pragma unroll
            for (int mt = 1; mt < 4; ++mt) {
                int mm = m0 + mt * 16 + l15;
                if (p[mt] > v1) { v2 = v1; i2 = i1; v1 = p[mt]; i1 = mm; }
                else if (p[mt] > v2) { v2 = p[mt]; i2 = mm; }
            }
#pragma unroll
            for (int d = 1; d < 16; d <<= 1) {
                float w1 = __shfl_xor(v1, d); int j1 = __shfl_xor(i1, d);
                float w2 = __shfl_xor(v2, d); int j2 = __shfl_xor(i2, d);
                if (w1 > v1) {
                    if (v1 > w2) { v2 = v1; i2 = i1; } else { v2 = w2; i2 = j2; }
                    v1 = w1; i1 = j1;
                } else if (w1 > v2) { v2 = w1; i2 = j1; }
            }
            float rs = 0.f;
#pragma unroll
            for (int mt = 0; mt < 4; ++mt) rs += expf(p[mt] - v1);
#pragma unroll
            for (int d = 1; d < 16; d <<= 1) rs += __shfl_xor(rs, d);
            if (l15 == 0) {
                size_t o = ((size_t)(b * 32 + 2 * blockIdx.x + wx)) * NN + n0 + nt * 16 + quad * 4 + r;
                rpM[o] = v1; rpS[o] = rs; rpI[o] = i1; rpM2[o] = v2; rpI2[o] = i2;
            }
        }
    // col stats
#pragma unroll
    for (int mt = 0; mt < 4; ++mt) {
        float cm = -3.4e38f;
#pragma unroll
        for (int nt = 0; nt < 4; ++nt)
#pragma unroll
            for (int r = 0; r < 4; ++r)
                cm = fmaxf(cm, 2.f * acc[nt][mt][r] - xv[nt][r] - yv[mt]);
        cm = fmaxf(cm, __shfl_xor(cm, 16));
        cm = fmaxf(cm, __shfl_xor(cm, 32));
        float cs = 0.f;
#pragma unroll
        for (int nt = 0; nt < 4; ++nt)
#pragma unroll
            for (int r = 0; r < 4; ++r)
                cs += expf(2.f * acc[nt][mt][r] - xv[nt][r] - yv[mt] - cm);
        cs += __shfl_xor(cs, 16);
        cs += __shfl_xor(cs, 32);
        if (quad == 0) {
            size_t o = ((size_t)(b * 32 + 2 * blockIdx.y + wy)) * MM + m0 + mt * 16 + l15;
            cpM[o] = cm; cpS[o] = cs;
        }
    }
}

// ---------- P2: sRow partials (col-softmax sums) + sCol partials (row-softmax sums) ----------
__global__ __launch_bounds__(256, 2) void pass2_k(const unsigned short* __restrict__ A0,
                                                  const unsigned short* __restrict__ A1,
                                                  const unsigned short* __restrict__ A2,
                                                  const unsigned short* __restrict__ B0,
                                                  const unsigned short* __restrict__ B1,
                                                  const unsigned short* __restrict__ B2,
                                                  const float* __restrict__ xx,
                                                  const float* __restrict__ yy,
                                                  const float* __restrict__ rowmax,
                                                  const float* __restrict__ rowsum,
                                                  const float* __restrict__ colmax,
                                                  const float* __restrict__ colsum,
                                                  float* __restrict__ sRowp, float* __restrict__ sColp) {
    WAVE_IDS
    v4f acc[4][4];
#pragma unroll
    for (int i = 0; i < 4; ++i)
#pragma unroll
        for (int j = 0; j < 4; ++j) acc[i][j] = (v4f){0.f, 0.f, 0.f, 0.f};
    gemm_main(A0, A1, A2, B0, B1, B2, bB, n0, m0, l15, quad, acc);
    float xv[4][4], yv[4], cm[4], ci[4], rmx[4][4], rin[4][4];
#pragma unroll
    for (int nt = 0; nt < 4; ++nt)
#pragma unroll
        for (int r = 0; r < 4; ++r) {
            int n = n0 + nt * 16 + quad * 4 + r;
            xv[nt][r] = xx[bB + n];
            rmx[nt][r] = rowmax[bB + n];
            rin[nt][r] = 1.f / rowsum[bB + n];
        }
#pragma unroll
    for (int mt = 0; mt < 4; ++mt) {
        int m = m0 + mt * 16 + l15;
        yv[mt] = yy[bB + m];
        cm[mt] = colmax[bB + m];
        ci[mt] = 1.f / colsum[bB + m];
    }
#pragma unroll
    for (int nt = 0; nt < 4; ++nt)
#pragma unroll
        for (int r = 0; r < 4; ++r) {
            float s = 0.f;
#pragma unroll
            for (int mt = 0; mt < 4; ++mt)
                s += expf(2.f * acc[nt][mt][r] - xv[nt][r] - yv[mt] - cm[mt]) * ci[mt];
#pragma unroll
            for (int d = 1; d < 16; d <<= 1) s += __shfl_xor(s, d);
            if (l15 == 0)
                sRowp[((size_t)(b * 32 + 2 * blockIdx.x + wx)) * NN + n0 + nt * 16 + quad * 4 + r] = s;
        }
#pragma unroll
    for (int mt = 0; mt < 4; ++mt) {
        float s = 0.f;
#pragma unroll
        for (int nt = 0; nt < 4; ++nt)
#pragma unroll
            for (int r = 0; r < 4; ++r)
                s += expf(2.f * acc[nt][mt][r] - xv[nt][r] - yv[mt] - rmx[nt][r]) * rin[nt][r];
        s += __shfl_xor(s, 16);
        s += __shfl_xor(s, 32);
        if (quad == 0)
            sColp[((size_t)(b * 32 + 2 * blockIdx.y + wy)) * MM + m0 + mt * 16 + l15] = s;
    }
}

// ---------- P3: corr partials (kept-weight sums and tgt dots) ----------
__global__ __launch_bounds__(256, 2) void pass3_k(const unsigned short* __restrict__ A0,
                                                  const unsigned short* __restrict__ A1,
                                                  const unsigned short* __restrict__ A2,
                                                  const unsigned short* __restrict__ B0,
                                                  const unsigned short* __restrict__ B1,
                                                  const unsigned short* __restrict__ B2,
                                                  const float* __restrict__ xx,
                                                  const float* __restrict__ yy,
                                                  const float* __restrict__ rowmax,
                                                  const float* __restrict__ rowsum,
                                                  const int* __restrict__ rowamax,
                                                  const float* __restrict__ sRow,
                                                  const float* __restrict__ sCol,
                                                  const float* __restrict__ rth,
                                                  const float* __restrict__ cth,
                                                  const float* __restrict__ tgt,
                                                  float* __restrict__ csP, float* __restrict__ d0P,
                                                  float* __restrict__ d1P, float* __restrict__ d2P) {
    WAVE_IDS
    v4f acc[4][4];
#pragma unroll
    for (int i = 0; i < 4; ++i)
#pragma unroll
        for (int j = 0; j < 4; ++j) acc[i][j] = (v4f){0.f, 0.f, 0.f, 0.f};
    gemm_main(A0, A1, A2, B0, B1, B2, bB, n0, m0, l15, quad, acc);
    float rthv = rth[b], cthv = cth[b];
    float xv[4][4], rmx[4][4], rin[4][4];
    int kidx[4][4]; bool msrc[4][4];
#pragma unroll
    for (int nt = 0; nt < 4; ++nt)
#pragma unroll
        for (int r = 0; r < 4; ++r) {
            int n = n0 + nt * 16 + quad * 4 + r;
            xv[nt][r] = xx[bB + n];
            rmx[nt][r] = rowmax[bB + n];
            rin[nt][r] = 1.f / rowsum[bB + n];
            kidx[nt][r] = rowamax[bB + n];
            msrc[nt][r] = sRow[bB + n] < rthv;
        }
    float yv[4], t0[4], t1[4], t2[4]; bool mtgt[4]; int mg[4];
#pragma unroll
    for (int mt = 0; mt < 4; ++mt) {
        int m = m0 + mt * 16 + l15;
        mg[mt] = m;
        yv[mt] = yy[bB + m];
        mtgt[mt] = sCol[bB + m] < cthv;
        t0[mt] = tgt[((size_t)(b * 3 + 0)) * MM + m];
        t1[mt] = tgt[((size_t)(b * 3 + 1)) * MM + m];
        t2[mt] = tgt[((size_t)(b * 3 + 2)) * MM + m];
    }
#pragma unroll
    for (int nt = 0; nt < 4; ++nt)
#pragma unroll
        for (int r = 0; r < 4; ++r) {
            float cs = 0.f, e0 = 0.f, e1 = 0.f, e2 = 0.f;
            bool ms = msrc[nt][r];
#pragma unroll
            for (int mt = 0; mt < 4; ++mt) {
                float pdv = 2.f * acc[nt][mt][r] - xv[nt][r] - yv[mt];
                bool keep = ms || mtgt[mt] || (mg[mt] == kidx[nt][r]);
                if (keep) {
                    float s = expf(pdv - rmx[nt][r]) * rin[nt][r];
                    cs += s; e0 += s * t0[mt]; e1 += s * t1[mt]; e2 += s * t2[mt];
                }
            }
#pragma unroll
            for (int d = 1; d < 16; d <<= 1) {
                cs += __shfl_xor(cs, d); e0 += __shfl_xor(e0, d);
                e1 += __shfl_xor(e1, d); e2 += __shfl_xor(e2, d);
            }
            if (l15 == 0) {
                size_t o = ((size_t)(b * 32 + 2 * blockIdx.x + wx)) * NN + n0 + nt * 16 + quad * 4 + r;
                csP[o] = cs; d0P[o] = e0; d1P[o] = e1; d2P[o] = e2;
            }
        }
}

// ---------- combine row partials (merge top-2 + softmax stats) ----------
__global__ __launch_bounds__(256) void comb_row_k(const float* __restrict__ rpM,
                                                  const float* __restrict__ rpS,
                                                  const int* __restrict__ rpI,
                                                  const float* __restrict__ rpM2,
                                                  const int* __restrict__ rpI2,
                                                  float* __restrict__ rowmax,
                                                  float* __restrict__ rowsum,
                                                  int* __restrict__ rowI1,
                                                  int* __restrict__ rowI2) {
    int b = blockIdx.y;
    int n = blockIdx.x * 256 + threadIdx.x;
    float V1 = -3.4e38f, V2 = -3.4e38f; int I1 = 0, I2 = 0;
#pragma unroll
    for (int k = 0; k < 32; ++k) {
        size_t o = ((size_t)(b * 32 + k)) * NN + n;
        float w1 = rpM[o], w2 = rpM2[o]; int j1 = rpI[o], j2 = rpI2[o];
        if (w1 > V1) {
            if (V1 > w2) { V2 = V1; I2 = I1; } else { V2 = w2; I2 = j2; }
            V1 = w1; I1 = j1;
        } else if (w1 > V2) { V2 = w1; I2 = j1; }
    }
    float S = 0.f;
#pragma unroll
    for (int k = 0; k < 32; ++k) {
        size_t o = ((size_t)(b * 32 + k)) * NN + n;
        S += rpS[o] * expf(rpM[o] - V1);
    }
    rowmax[b * NN + n] = V1; rowsum[b * NN + n] = S;
    rowI1[b * NN + n] = I1; rowI2[b * NN + n] = I2;
}

// ---------- exact fp32 rescue: pick true argmax among the top-2 candidates ----------
__global__ __launch_bounds__(256) void fix_k(const float* __restrict__ src_emb,
                                             const float* __restrict__ tgt_emb,
                                             const float* __restrict__ yy,
                                             const int* __restrict__ rowI1,
                                             const int* __restrict__ rowI2,
                                             int* __restrict__ rowamax) {
    int b = blockIdx.y;
    int n = blockIdx.x * 256 + threadIdx.x;
    int i1 = rowI1[b * NN + n], i2 = rowI2[b * NN + n];
    const float* S = src_emb + (size_t)b * CC * NN;
    const float* T = tgt_emb + (size_t)b * CC * MM;
    float d1 = 0.f, d2 = 0.f;
#pragma unroll
    for (int c = 0; c < CC; ++c) {
        float s = S[(size_t)c * NN + n];
        d1 += s * T[(size_t)c * MM + i1];
        d2 += s * T[(size_t)c * MM + i2];
    }
    float p1 = 2.f * d1 - yy[b * MM + i1];   // xx[n] cancels in the comparison
    float p2 = 2.f * d2 - yy[b * MM + i2];
    int best;
    if (p2 > p1) best = i2;
    else if (p1 > p2) best = i1;
    else best = (i1 < i2) ? i1 : i2;
    rowamax[b * NN + n] = best;
}

// ---------- combine col partials ----------
__global__ __launch_bounds__(256) void comb_col_k(const float* __restrict__ cpM,
                                                  const float* __restrict__ cpS,
                                                  float* __restrict__ colmax,
                                                  float* __restrict__ colsum) {
    int b = blockIdx.y;
    int m = blockIdx.x * 256 + threadIdx.x;
    float M = -3.4e38f;
#pragma unroll
    for (int k = 0; k < 32; ++k) M = fmaxf(M, cpM[((size_t)(b * 32 + k)) * MM + m]);
    float S = 0.f;
#pragma unroll
    for (int k = 0; k < 32; ++k) {
        size_t o = ((size_t)(b * 32 + k)) * MM + m;
        S += cpS[o] * expf(cpM[o] - M);
    }
    colmax[b * MM + m] = M; colsum[b * MM + m] = S;
}

// ---------- combine sRow/sCol partials ----------
__global__ __launch_bounds__(256) void comb_s_k(const float* __restrict__ sRowp,
                                                const float* __restrict__ sColp,
                                                float* __restrict__ sRow,
                                                float* __restrict__ sCol) {
    int b = blockIdx.y, which = blockIdx.z;
    int i = blockIdx.x * 256 + threadIdx.x;
    const float* p = which ? sColp : sRowp;
    float s = 0.f;
#pragma unroll
    for (int k = 0; k < 32; ++k) s += p[((size_t)(b * 32 + k)) * 2048 + i];
    (which ? sCol : sRow)[b * 2048 + i] = s;
}

// ---------- 614-th smallest via binary search on float bits ----------
__global__ __launch_bounds__(64) void select_k(const float* __restrict__ sRow,
                                               const float* __restrict__ sCol,
                                               float* __restrict__ rth,
                                               float* __restrict__ cth) {
    int kind = blockIdx.x, b = blockIdx.y, t = threadIdx.x;
    const float* vals = (kind == 0) ? (sRow + b * NN) : (sCol + b * MM);
    float v[32];
#pragma unroll
    for (int i = 0; i < 32; ++i) v[i] = vals[t + (i << 6)];
    unsigned lo = 0u, hi = 0x7F800000u;
    while (lo < hi) {
        unsigned mid = lo + ((hi - lo) >> 1);
        float pv = __uint_as_float(mid);
        int c = 0;
#pragma unroll
        for (int i = 0; i < 32; ++i) c += (v[i] <= pv) ? 1 : 0;
#pragma unroll
        for (int off = 32; off > 0; off >>= 1) c += __shfl_down(c, off);
        c = __shfl(c, 0);
        if (c >= KSEL + 1) hi = mid; else lo = mid + 1;
    }
    if (t == 0) { if (kind == 0) rth[b] = __uint_as_float(lo); else cth[b] = __uint_as_float(lo); }
}

// ---------- masks + src_weight ----------
__global__ __launch_bounds__(256) void masks_k(const float* __restrict__ sRow,
                                               const float* __restrict__ sCol,
                                               const float* __restrict__ rth,
                                               const float* __restrict__ cth,
                                               float* __restrict__ out) {
    int b = blockIdx.x, t = threadIdx.x;
    float r = rth[b], c = cth[b];
    int cnt = 0;
    bool ms[8];
#pragma unroll
    for (int i = 0; i < 8; ++i) {
        int n = t + (i << 8);
        ms[i] = sRow[b * NN + n] < r;
        out[OUT_MS + b * NN + n] = ms[i] ? 1.f : 0.f;
        out[OUT_MT + b * MM + n] = (sCol[b * MM + n] < c) ? 1.f : 0.f;
        cnt += ms[i] ? 0 : 1;
    }
#pragma unroll
    for (int off = 32; off > 0; off >>= 1) cnt += __shfl_down(cnt, off);
    __shared__ int wcnt[4];
    int wave = t >> 6, lane = t & 63;
    if (lane == 0) wcnt[wave] = cnt;
    __syncthreads();
    float inv = 1.f / (float)(wcnt[0] + wcnt[1] + wcnt[2] + wcnt[3]);
#pragma unroll
    for (int i = 0; i < 8; ++i) {
        int n = t + (i << 8);
        out[OUT_W + b * NN + n] = ms[i] ? 0.f : inv;
    }
}

// ---------- combine corr partials -> src_corr ----------
__global__ __launch_bounds__(256) void comb_corr_k(const float* __restrict__ csP,
                                                   const float* __restrict__ d0P,
                                                   const float* __restrict__ d1P,
                                                   const float* __restrict__ d2P,
                                                   float* __restrict__ out) {
    int b = blockIdx.y;
    int n = blockIdx.x * 256 + threadIdx.x;
    float cs = 0.f, e0 = 0.f, e1 = 0.f, e2 = 0.f;
#pragma unroll
    for (int k = 0; k < 32; ++k) {
        size_t o = ((size_t)(b * 32 + k)) * NN + n;
        cs += csP[o]; e0 += d0P[o]; e1 += d1P[o]; e2 += d2P[o];
    }
    cs = (cs < 1e-5f) ? 1e-5f : cs;
    out[((size_t)(b * 3 + 0)) * NN + n] = e0 / cs;
    out[((size_t)(b * 3 + 1)) * NN + n] = e1 / cs;
    out[((size_t)(b * 3 + 2)) * NN + n] = e2 / cs;
}

extern "C" void kernel_launch(void* const* d_in, const int* in_sizes, int n_in,
                              void* d_out, int out_size, void* d_ws, size_t ws_size,
                              hipStream_t stream) {
    const float* src_emb = (const float*)d_in[0];
    const float* tgt_emb = (const float*)d_in[1];
    const float* tgt = (const float*)d_in[3];
    float* out = (float*)d_out;

    unsigned short* us = (unsigned short*)d_ws;
    const size_t TSZ = (size_t)BB * NN * 64;
    unsigned short* A0 = us;
    unsigned short* A1 = A0 + TSZ;
    unsigned short* A2 = A1 + TSZ;
    unsigned short* B0 = A2 + TSZ;
    unsigned short* B1 = B0 + TSZ;
    unsigned short* B2 = B1 + TSZ;
    float* f = (float*)(B2 + TSZ);
    const size_t P = (size_t)BB * 32 * NN;
    float* rpM = f;            f += P;
    float* rpS = f;            f += P;
    int*   rpI = (int*)f;      f += P;
    float* rpM2 = f;           f += P;
    int*   rpI2 = (int*)f;     f += P;
    float* cpM = f;            f += P;
    float* cpS = f;            f += P;
    float* sRowp = f;          f += P;
    float* sColp = f;          f += P;
    float* csP = f;            f += P;
    float* d0P = f;            f += P;
    float* d1P = f;            f += P;
    float* d2P = f;            f += P;
    float* xx = f;             f += BB * NN;
    float* yy = f;             f += BB * MM;
    float* rowmax = f;         f += BB * NN;
    float* rowsum = f;         f += BB * NN;
    int*   rowamax = (int*)f;  f += BB * NN;
    int*   rowI1 = (int*)f;    f += BB * NN;
    int*   rowI2 = (int*)f;    f += BB * NN;
    float* colmax = f;         f += BB * MM;
    float* colsum = f;         f += BB * MM;
    float* sRow = f;           f += BB * NN;
    float* sCol = f;           f += BB * MM;
    float* rth = f;            f += BB;
    float* cth = f;            f += BB;

    split_k<<<dim3(NN / 64, BB), 256, 0, stream>>>(src_emb, A0, A1, A2, xx);
    split_k<<<dim3(MM / 64, BB), 256, 0, stream>>>(tgt_emb, B0, B1, B2, yy);
    pass1_k<<<dim3(MM / 128, NN / 128, BB), 256, 0, stream>>>(A0, A1, A2, B0, B1, B2, xx, yy,
                                                              rpM, rpS, rpI, rpM2, rpI2, cpM, cpS);
    comb_row_k<<<dim3(NN / 256, BB), 256, 0, stream>>>(rpM, rpS, rpI, rpM2, rpI2,
                                                       rowmax, rowsum, rowI1, rowI2);
    comb_col_k<<<dim3(MM / 256, BB), 256, 0, stream>>>(cpM, cpS, colmax, colsum);
    fix_k<<<dim3(NN / 256, BB), 256, 0, stream>>>(src_emb, tgt_emb, yy, rowI1, rowI2, rowamax);
    pass2_k<<<dim3(MM / 128, NN / 128, BB), 256, 0, stream>>>(A0, A1, A2, B0, B1, B2, xx, yy,
                                                              rowmax, rowsum, colmax, colsum,
                                                              sRowp, sColp);
    comb_s_k<<<dim3(2048 / 256, BB, 2), 256, 0, stream>>>(sRowp, sColp, sRow, sCol);
    select_k<<<dim3(2, BB), 64, 0, stream>>>(sRow, sCol, rth, cth);
    masks_k<<<dim3(BB), 256, 0, stream>>>(sRow, sCol, rth, cth, out);
    pass3_k<<<dim3(MM / 128, NN / 128, BB), 256, 0, stream>>>(A0, A1, A2, B0, B1, B2, xx, yy,
                                                              rowmax, rowsum, rowamax, sRow, sCol,
                                                              rth, cth, tgt, csP, d0P, d1P, d2P);
    comb_corr_k<<<dim3(NN / 256, BB), 256, 0, stream>>>(csP, d0P, d1P, d2P, out);
}

// Round 6
// 369.216 us; speedup vs baseline: 1.2026x; 1.2026x over previous
//
#include <hip/hip_runtime.h>

// EPCOR eval path on MI355X — MFMA recompute version (no pd materialization).
// pd regenerated per pass from fp32->3xbf16 split operands (6-term MFMA;
// pass3 uses 3-term). Row-argmax rescued exactly in fp32 (top-2 + fix_k).
#define BB 8
#define CC 64
#define NN 2048
#define MM 2048
#define KSEL 613            // 0-based index of the 614-th smallest (int(2048*0.3)=614)

// Output layout (floats): src_corr [B,3,N] | src_weight [B,N] | mask_src [B,N] | mask_tgt [B,M]
#define OUT_W  (BB * 3 * NN)
#define OUT_MS (OUT_W + BB * NN)
#define OUT_MT (OUT_MS + BB * NN)

typedef __attribute__((ext_vector_type(8))) short v8s;
typedef __attribute__((ext_vector_type(4))) float v4f;

static __device__ inline unsigned short f2bf(float x) {
    union { float f; unsigned u; } v; v.f = x;
    unsigned r = v.u + 0x7FFF + ((v.u >> 16) & 1);   // round-to-nearest-even
    return (unsigned short)(r >> 16);
}
static __device__ inline float bf2f(unsigned short h) {
    union { float f; unsigned u; } v; v.u = ((unsigned)h) << 16; return v.f;
}

// ---------- K0: split fp32 [B,64,L] -> 3x bf16 transposed [B,L,64] + sq-norms ----------
__global__ __launch_bounds__(256) void split_k(const float* __restrict__ in,
                                               unsigned short* __restrict__ T0,
                                               unsigned short* __restrict__ T1,
                                               unsigned short* __restrict__ T2,
                                               float* __restrict__ nrm) {
    __shared__ float tile[64][64];  // [c][n]
    __shared__ float xs[64][4];
    int b = blockIdx.y;
    int n0 = blockIdx.x << 6;
    int t = threadIdx.x;
    int c4 = t >> 6, nl = t & 63;
#pragma unroll
    for (int r = 0; r < 16; ++r) {
        int c = (r << 2) + c4;
        tile[c][nl] = in[((size_t)(b * CC + c)) * NN + n0 + nl];
    }
    __syncthreads();
    int n = t >> 2, cq = t & 3;
    size_t base = ((size_t)(b * NN + n0 + n)) * 64 + cq * 16;
    float ss = 0.f;
#pragma unroll
    for (int j = 0; j < 16; ++j) {
        float a = tile[cq * 16 + j][n];
        ss += a * a;
        unsigned short h0 = f2bf(a);
        float r1 = a - bf2f(h0);
        unsigned short h1 = f2bf(r1);
        float r2 = r1 - bf2f(h1);
        unsigned short h2 = f2bf(r2);
        T0[base + j] = h0; T1[base + j] = h1; T2[base + j] = h2;
    }
    xs[n][cq] = ss;
    __syncthreads();
    if (t < 64) nrm[b * NN + n0 + t] = xs[t][0] + xs[t][1] + xs[t][2] + xs[t][3];
}

// ---------- shared mainloop: 64x64 wave tile, 6-term bf16 MFMA, K=64 ----------
__device__ inline void gemm_main(const unsigned short* __restrict__ A0,
                                 const unsigned short* __restrict__ A1,
                                 const unsigned short* __restrict__ A2,
                                 const unsigned short* __restrict__ B0,
                                 const unsigned short* __restrict__ B1,
                                 const unsigned short* __restrict__ B2,
                                 int bB, int n0, int m0, int l15, int quad,
                                 v4f acc[4][4]) {
#pragma unroll
    for (int ks = 0; ks < 2; ++ks) {
        size_t ko = ks * 32 + quad * 8;
        size_t ra[4], rb[4];
#pragma unroll
        for (int q = 0; q < 4; ++q) {
            ra[q] = ((size_t)(bB + n0 + q * 16 + l15)) * 64 + ko;
            rb[q] = ((size_t)(bB + m0 + q * 16 + l15)) * 64 + ko;
        }
        v8s a0f[4], a1f[4], a2f[4], b0f[4], b1f[4], b2f[4];
#pragma unroll
        for (int q = 0; q < 4; ++q) { a0f[q] = *(const v8s*)(A0 + ra[q]); b0f[q] = *(const v8s*)(B0 + rb[q]); }
#pragma unroll
        for (int nt = 0; nt < 4; ++nt)
#pragma unroll
            for (int mt = 0; mt < 4; ++mt)
                acc[nt][mt] = __builtin_amdgcn_mfma_f32_16x16x32_bf16(a0f[nt], b0f[mt], acc[nt][mt], 0, 0, 0);
#pragma unroll
        for (int q = 0; q < 4; ++q) b1f[q] = *(const v8s*)(B1 + rb[q]);
#pragma unroll
        for (int nt = 0; nt < 4; ++nt)
#pragma unroll
            for (int mt = 0; mt < 4; ++mt)
                acc[nt][mt] = __builtin_amdgcn_mfma_f32_16x16x32_bf16(a0f[nt], b1f[mt], acc[nt][mt], 0, 0, 0);
#pragma unroll
        for (int q = 0; q < 4; ++q) b2f[q] = *(const v8s*)(B2 + rb[q]);
#pragma unroll
        for (int nt = 0; nt < 4; ++nt)
#pragma unroll
            for (int mt = 0; mt < 4; ++mt)
                acc[nt][mt] = __builtin_amdgcn_mfma_f32_16x16x32_bf16(a0f[nt], b2f[mt], acc[nt][mt], 0, 0, 0);
#pragma unroll
        for (int q = 0; q < 4; ++q) a1f[q] = *(const v8s*)(A1 + ra[q]);
#pragma unroll
        for (int nt = 0; nt < 4; ++nt)
#pragma unroll
            for (int mt = 0; mt < 4; ++mt)
                acc[nt][mt] = __builtin_amdgcn_mfma_f32_16x16x32_bf16(a1f[nt], b0f[mt], acc[nt][mt], 0, 0, 0);
#pragma unroll
        for (int nt = 0; nt < 4; ++nt)
#pragma unroll
            for (int mt = 0; mt < 4; ++mt)
                acc[nt][mt] = __builtin_amdgcn_mfma_f32_16x16x32_bf16(a1f[nt], b1f[mt], acc[nt][mt], 0, 0, 0);
#pragma unroll
        for (int q = 0; q < 4; ++q) a2f[q] = *(const v8s*)(A2 + ra[q]);
#pragma unroll
        for (int nt = 0; nt < 4; ++nt)
#pragma unroll
            for (int mt = 0; mt < 4; ++mt)
                acc[nt][mt] = __builtin_amdgcn_mfma_f32_16x16x32_bf16(a2f[nt], b0f[mt], acc[nt][mt], 0, 0, 0);
    }
}

// ---------- 3-term mainloop (pass3): a0b0 + a0b1 + a1b0, error ~1.5e-4 ----------
__device__ inline void gemm_main3(const unsigned short* __restrict__ A0,
                                  const unsigned short* __restrict__ A1,
                                  const unsigned short* __restrict__ B0,
                                  const unsigned short* __restrict__ B1,
                                  int bB, int n0, int m0, int l15, int quad,
                                  v4f acc[4][4]) {
#pragma unroll
    for (int ks = 0; ks < 2; ++ks) {
        size_t ko = ks * 32 + quad * 8;
        size_t ra[4], rb[4];
#pragma unroll
        for (int q = 0; q < 4; ++q) {
            ra[q] = ((size_t)(bB + n0 + q * 16 + l15)) * 64 + ko;
            rb[q] = ((size_t)(bB + m0 + q * 16 + l15)) * 64 + ko;
        }
        v8s a0f[4], a1f[4], b0f[4], b1f[4];
#pragma unroll
        for (int q = 0; q < 4; ++q) { a0f[q] = *(const v8s*)(A0 + ra[q]); b0f[q] = *(const v8s*)(B0 + rb[q]); }
#pragma unroll
        for (int nt = 0; nt < 4; ++nt)
#pragma unroll
            for (int mt = 0; mt < 4; ++mt)
                acc[nt][mt] = __builtin_amdgcn_mfma_f32_16x16x32_bf16(a0f[nt], b0f[mt], acc[nt][mt], 0, 0, 0);
#pragma unroll
        for (int q = 0; q < 4; ++q) b1f[q] = *(const v8s*)(B1 + rb[q]);
#pragma unroll
        for (int nt = 0; nt < 4; ++nt)
#pragma unroll
            for (int mt = 0; mt < 4; ++mt)
                acc[nt][mt] = __builtin_amdgcn_mfma_f32_16x16x32_bf16(a0f[nt], b1f[mt], acc[nt][mt], 0, 0, 0);
#pragma unroll
        for (int q = 0; q < 4; ++q) a1f[q] = *(const v8s*)(A1 + ra[q]);
#pragma unroll
        for (int nt = 0; nt < 4; ++nt)
#pragma unroll
            for (int mt = 0; mt < 4; ++mt)
                acc[nt][mt] = __builtin_amdgcn_mfma_f32_16x16x32_bf16(a1f[nt], b0f[mt], acc[nt][mt], 0, 0, 0);
    }
}

#define WAVE_IDS \
    int t = threadIdx.x; int lane = t & 63; int wave = t >> 6; \
    int wx = wave & 1, wy = wave >> 1; \
    int l15 = lane & 15, quad = lane >> 4; \
    int b = blockIdx.z; int bB = b * NN; \
    int n0 = blockIdx.y * 128 + wy * 64; \
    int m0 = blockIdx.x * 128 + wx * 64;

// ---------- P1: row stats (top-2 value/index, sumexp) + col stats partials ----------
__global__ __launch_bounds__(256, 2) void pass1_k(const unsigned short* __restrict__ A0,
                                                  const unsigned short* __restrict__ A1,
                                                  const unsigned short* __restrict__ A2,
                                                  const unsigned short* __restrict__ B0,
                                                  const unsigned short* __restrict__ B1,
                                                  const unsigned short* __restrict__ B2,
                                                  const float* __restrict__ xx,
                                                  const float* __restrict__ yy,
                                                  float* __restrict__ rpM, float* __restrict__ rpS,
                                                  int* __restrict__ rpI,
                                                  float* __restrict__ rpM2, int* __restrict__ rpI2,
                                                  float* __restrict__ cpM, float* __restrict__ cpS) {
    __shared__ float stage[4][16 * 66];   // per-wave 16x64 pd sub-tile, +2 pad
    WAVE_IDS
    v4f acc[4][4];
#pragma unroll
    for (int i = 0; i < 4; ++i)
#pragma unroll
        for (int j = 0; j < 4; ++j) acc[i][j] = (v4f){0.f, 0.f, 0.f, 0.f};
    gemm_main(A0, A1, A2, B0, B1, B2, bB, n0, m0, l15, quad, acc);
    float xv[4][4], yv[4];
#pragma unroll
    for (int nt = 0; nt < 4; ++nt)
#pragma unroll
        for (int r = 0; r < 4; ++r) xv[nt][r] = xx[bB + n0 + nt * 16 + quad * 4 + r];
#pragma unroll
    for (int mt = 0; mt < 4; ++mt) yv[mt] = yy[bB + m0 + mt * 16 + l15];
    // ---- col stats: in-lane over 16 rows, then 2 shuffles across quads ----
#pragma unroll
    for (int mt = 0; mt < 4; ++mt) {
        float cm = -3.4e38f;
#pragma unroll
        for (int nt = 0; nt < 4; ++nt)
#pragma unroll
            for (int r = 0; r < 4; ++r)
                cm = fmaxf(cm, 2.f * acc[nt][mt][r] - xv[nt][r] - yv[mt]);
        cm = fmaxf(cm, __shfl_xor(cm, 16));
        cm = fmaxf(cm, __shfl_xor(cm, 32));
        float cs = 0.f;
#pragma unroll
        for (int nt = 0; nt < 4; ++nt)
#pragma unroll
            for (int r = 0; r < 4; ++r)
                cs += __expf(2.f * acc[nt][mt][r] - xv[nt][r] - yv[mt] - cm);
        cs += __shfl_xor(cs, 16);
        cs += __shfl_xor(cs, 32);
        if (quad == 0) {
            size_t o = ((size_t)(b * 32 + 2 * blockIdx.y + wy)) * MM + m0 + mt * 16 + l15;
            cpM[o] = cm; cpS[o] = cs;
        }
    }
    // ---- row stats: LDS transpose per nt-round; lane owns a 16-col chunk of one row ----
    float* st = stage[wave];
    int R = lane >> 2, C = lane & 3;
#pragma unroll
    for (int nt = 0; nt < 4; ++nt) {
        __syncthreads();
#pragma unroll
        for (int r = 0; r < 4; ++r)
#pragma unroll
            for (int mt = 0; mt < 4; ++mt)
                st[(quad * 4 + r) * 66 + mt * 16 + l15] = 2.f * acc[nt][mt][r] - xv[nt][r] - yv[mt];
        __syncthreads();
        float v[16];
#pragma unroll
        for (int k = 0; k < 4; ++k)
            *(float4*)(v + 4 * k) = *(const float4*)(st + R * 66 + C * 16 + 4 * k);
        float v1 = v[0]; int i1 = 0;
        float v2 = -3.4e38f; int i2 = 0;
#pragma unroll
        for (int k = 1; k < 16; ++k) {
            if (v[k] > v1) { v2 = v1; i2 = i1; v1 = v[k]; i1 = k; }
            else if (v[k] > v2) { v2 = v[k]; i2 = k; }
        }
        i1 += m0 + C * 16; i2 += m0 + C * 16;
        float S = 0.f;
#pragma unroll
        for (int k = 0; k < 16; ++k) S += __expf(v[k] - v1);
        // merge the 4 chunks of each row (lanes R*4 + C, C=0..3)
#pragma unroll
        for (int d = 1; d < 4; d <<= 1) {
            float oM = __shfl_xor(v1, d);
            float oS = __shfl_xor(S, d);
            int oi1 = __shfl_xor(i1, d);
            float ov2 = __shfl_xor(v2, d);
            int oi2 = __shfl_xor(i2, d);
            float nM = fmaxf(v1, oM);
            S = S * __expf(v1 - nM) + oS * __expf(oM - nM);
            if (oM > v1) {
                if (v1 > ov2) { v2 = v1; i2 = i1; } else { v2 = ov2; i2 = oi2; }
                v1 = oM; i1 = oi1;
            } else if (oM > v2) { v2 = oM; i2 = oi1; }
        }
        if (C == 0) {
            size_t o = ((size_t)(b * 32 + 2 * blockIdx.x + wx)) * NN + n0 + nt * 16 + R;
            rpM[o] = v1; rpS[o] = S; rpI[o] = i1; rpM2[o] = v2; rpI2[o] = i2;
        }
    }
}

// ---------- P2: sRow partials (col-softmax sums) + sCol partials (row-softmax sums) ----------
__global__ __launch_bounds__(256, 2) void pass2_k(const unsigned short* __restrict__ A0,
                                                  const unsigned short* __restrict__ A1,
                                                  const unsigned short* __restrict__ A2,
                                                  const unsigned short* __restrict__ B0,
                                                  const unsigned short* __restrict__ B1,
                                                  const unsigned short* __restrict__ B2,
                                                  const float* __restrict__ xx,
                                                  const float* __restrict__ yy,
                                                  const float* __restrict__ rowmax,
                                                  const float* __restrict__ rowsum,
                                                  const float* __restrict__ colmax,
                                                  const float* __restrict__ colsum,
                                                  float* __restrict__ sRowp, float* __restrict__ sColp) {
    WAVE_IDS
    v4f acc[4][4];
#pragma unroll
    for (int i = 0; i < 4; ++i)
#pragma unroll
        for (int j = 0; j < 4; ++j) acc[i][j] = (v4f){0.f, 0.f, 0.f, 0.f};
    gemm_main(A0, A1, A2, B0, B1, B2, bB, n0, m0, l15, quad, acc);
    float xv[4][4], yv[4], cm[4], ci[4], rmx[4][4], rin[4][4];
#pragma unroll
    for (int nt = 0; nt < 4; ++nt)
#pragma unroll
        for (int r = 0; r < 4; ++r) {
            int n = n0 + nt * 16 + quad * 4 + r;
            xv[nt][r] = xx[bB + n];
            rmx[nt][r] = rowmax[bB + n];
            rin[nt][r] = 1.f / rowsum[bB + n];
        }
#pragma unroll
    for (int mt = 0; mt < 4; ++mt) {
        int m = m0 + mt * 16 + l15;
        yv[mt] = yy[bB + m];
        cm[mt] = colmax[bB + m];
        ci[mt] = 1.f / colsum[bB + m];
    }
    // sCol partial: per col, in-lane over 16 rows + 2 shuffles
#pragma unroll
    for (int mt = 0; mt < 4; ++mt) {
        float s = 0.f;
#pragma unroll
        for (int nt = 0; nt < 4; ++nt)
#pragma unroll
            for (int r = 0; r < 4; ++r)
                s += __expf(2.f * acc[nt][mt][r] - xv[nt][r] - yv[mt] - rmx[nt][r]) * rin[nt][r];
        s += __shfl_xor(s, 16);
        s += __shfl_xor(s, 32);
        if (quad == 0)
            sColp[((size_t)(b * 32 + 2 * blockIdx.y + wy)) * MM + m0 + mt * 16 + l15] = s;
    }
    // sRow partial: per nt, batched butterfly over the 16 lanes
#pragma unroll
    for (int nt = 0; nt < 4; ++nt) {
        float s[4];
#pragma unroll
        for (int r = 0; r < 4; ++r) {
            float a = 0.f;
#pragma unroll
            for (int mt = 0; mt < 4; ++mt)
                a += __expf(2.f * acc[nt][mt][r] - xv[nt][r] - yv[mt] - cm[mt]) * ci[mt];
            s[r] = a;
        }
#pragma unroll
        for (int d = 1; d < 16; d <<= 1)
#pragma unroll
            for (int r = 0; r < 4; ++r) s[r] += __shfl_xor(s[r], d);
        if (l15 == 0) {
            size_t o = ((size_t)(b * 32 + 2 * blockIdx.x + wx)) * NN + n0 + nt * 16 + quad * 4;
            *(float4*)&sRowp[o] = make_float4(s[0], s[1], s[2], s[3]);
        }
    }
}

// ---------- P3: corr partials (kept-weight sums and tgt dots), 3-term GEMM ----------
__global__ __launch_bounds__(256, 2) void pass3_k(const unsigned short* __restrict__ A0,
                                                  const unsigned short* __restrict__ A1,
                                                  const unsigned short* __restrict__ B0,
                                                  const unsigned short* __restrict__ B1,
                                                  const float* __restrict__ xx,
                                                  const float* __restrict__ yy,
                                                  const float* __restrict__ rowmax,
                                                  const float* __restrict__ rowsum,
                                                  const int* __restrict__ rowamax,
                                                  const float* __restrict__ sRow,
                                                  const float* __restrict__ sCol,
                                                  const float* __restrict__ rth,
                                                  const float* __restrict__ cth,
                                                  const float* __restrict__ tgt,
                                                  float* __restrict__ csP, float* __restrict__ d0P,
                                                  float* __restrict__ d1P, float* __restrict__ d2P) {
    WAVE_IDS
    v4f acc[4][4];
#pragma unroll
    for (int i = 0; i < 4; ++i)
#pragma unroll
        for (int j = 0; j < 4; ++j) acc[i][j] = (v4f){0.f, 0.f, 0.f, 0.f};
    gemm_main3(A0, A1, B0, B1, bB, n0, m0, l15, quad, acc);
    float rthv = rth[b], cthv = cth[b];
    float yv[4], t0[4], t1[4], t2[4]; bool mtgt[4]; int mg[4];
#pragma unroll
    for (int mt = 0; mt < 4; ++mt) {
        int m = m0 + mt * 16 + l15;
        mg[mt] = m;
        yv[mt] = yy[bB + m];
        mtgt[mt] = sCol[bB + m] < cthv;
        t0[mt] = tgt[((size_t)(b * 3 + 0)) * MM + m];
        t1[mt] = tgt[((size_t)(b * 3 + 1)) * MM + m];
        t2[mt] = tgt[((size_t)(b * 3 + 2)) * MM + m];
    }
#pragma unroll
    for (int nt = 0; nt < 4; ++nt) {
        float cs[4], e0[4], e1[4], e2[4];
#pragma unroll
        for (int r = 0; r < 4; ++r) {
            int n = n0 + nt * 16 + quad * 4 + r;
            float xvv = xx[bB + n];
            float rmx = rowmax[bB + n];
            float rin = 1.f / rowsum[bB + n];
            int kidx = rowamax[bB + n];
            bool ms = sRow[bB + n] < rthv;
            float a = 0.f, b0v = 0.f, b1v = 0.f, b2v = 0.f;
#pragma unroll
            for (int mt = 0; mt < 4; ++mt) {
                float pdv = 2.f * acc[nt][mt][r] - xvv - yv[mt];
                bool keep = ms || mtgt[mt] || (mg[mt] == kidx);
                if (keep) {
                    float s = __expf(pdv - rmx) * rin;
                    a += s; b0v += s * t0[mt]; b1v += s * t1[mt]; b2v += s * t2[mt];
                }
            }
            cs[r] = a; e0[r] = b0v; e1[r] = b1v; e2[r] = b2v;
        }
#pragma unroll
        for (int d = 1; d < 16; d <<= 1)
#pragma unroll
            for (int r = 0; r < 4; ++r) {
                cs[r] += __shfl_xor(cs[r], d);
                e0[r] += __shfl_xor(e0[r], d);
                e1[r] += __shfl_xor(e1[r], d);
                e2[r] += __shfl_xor(e2[r], d);
            }
        if (l15 == 0) {
            size_t o = ((size_t)(b * 32 + 2 * blockIdx.x + wx)) * NN + n0 + nt * 16 + quad * 4;
            *(float4*)&csP[o] = make_float4(cs[0], cs[1], cs[2], cs[3]);
            *(float4*)&d0P[o] = make_float4(e0[0], e0[1], e0[2], e0[3]);
            *(float4*)&d1P[o] = make_float4(e1[0], e1[1], e1[2], e1[3]);
            *(float4*)&d2P[o] = make_float4(e2[0], e2[1], e2[2], e2[3]);
        }
    }
}

// ---------- combine row partials (merge top-2 + softmax stats) ----------
__global__ __launch_bounds__(256) void comb_row_k(const float* __restrict__ rpM,
                                                  const float* __restrict__ rpS,
                                                  const int* __restrict__ rpI,
                                                  const float* __restrict__ rpM2,
                                                  const int* __restrict__ rpI2,
                                                  float* __restrict__ rowmax,
                                                  float* __restrict__ rowsum,
                                                  int* __restrict__ rowI1,
                                                  int* __restrict__ rowI2) {
    int b = blockIdx.y;
    int n = blockIdx.x * 256 + threadIdx.x;
    float V1 = -3.4e38f, V2 = -3.4e38f; int I1 = 0, I2 = 0;
#pragma unroll
    for (int k = 0; k < 32; ++k) {
        size_t o = ((size_t)(b * 32 + k)) * NN + n;
        float w1 = rpM[o], w2 = rpM2[o]; int j1 = rpI[o], j2 = rpI2[o];
        if (w1 > V1) {
            if (V1 > w2) { V2 = V1; I2 = I1; } else { V2 = w2; I2 = j2; }
            V1 = w1; I1 = j1;
        } else if (w1 > V2) { V2 = w1; I2 = j1; }
    }
    float S = 0.f;
#pragma unroll
    for (int k = 0; k < 32; ++k) {
        size_t o = ((size_t)(b * 32 + k)) * NN + n;
        S += rpS[o] * __expf(rpM[o] - V1);
    }
    rowmax[b * NN + n] = V1; rowsum[b * NN + n] = S;
    rowI1[b * NN + n] = I1; rowI2[b * NN + n] = I2;
}

// ---------- exact fp32 rescue: pick true argmax among the top-2 candidates ----------
__global__ __launch_bounds__(256) void fix_k(const float* __restrict__ src_emb,
                                             const float* __restrict__ tgt_emb,
                                             const float* __restrict__ yy,
                                             const int* __restrict__ rowI1,
                                             const int* __restrict__ rowI2,
                                             int* __restrict__ rowamax) {
    int b = blockIdx.y;
    int n = blockIdx.x * 256 + threadIdx.x;
    int i1 = rowI1[b * NN + n], i2 = rowI2[b * NN + n];
    const float* S = src_emb + (size_t)b * CC * NN;
    const float* T = tgt_emb + (size_t)b * CC * MM;
    float d1 = 0.f, d2 = 0.f;
#pragma unroll
    for (int c = 0; c < CC; ++c) {
        float s = S[(size_t)c * NN + n];
        d1 += s * T[(size_t)c * MM + i1];
        d2 += s * T[(size_t)c * MM + i2];
    }
    float p1 = 2.f * d1 - yy[b * MM + i1];   // xx[n] cancels in the comparison
    float p2 = 2.f * d2 - yy[b * MM + i2];
    int best;
    if (p2 > p1) best = i2;
    else if (p1 > p2) best = i1;
    else best = (i1 < i2) ? i1 : i2;
    rowamax[b * NN + n] = best;
}

// ---------- combine col partials ----------
__global__ __launch_bounds__(256) void comb_col_k(const float* __restrict__ cpM,
                                                  const float* __restrict__ cpS,
                                                  float* __restrict__ colmax,
                                                  float* __restrict__ colsum) {
    int b = blockIdx.y;
    int m = blockIdx.x * 256 + threadIdx.x;
    float M = -3.4e38f;
#pragma unroll
    for (int k = 0; k < 32; ++k) M = fmaxf(M, cpM[((size_t)(b * 32 + k)) * MM + m]);
    float S = 0.f;
#pragma unroll
    for (int k = 0; k < 32; ++k) {
        size_t o = ((size_t)(b * 32 + k)) * MM + m;
        S += cpS[o] * __expf(cpM[o] - M);
    }
    colmax[b * MM + m] = M; colsum[b * MM + m] = S;
}

// ---------- combine sRow/sCol partials ----------
__global__ __launch_bounds__(256) void comb_s_k(const float* __restrict__ sRowp,
                                                const float* __restrict__ sColp,
                                                float* __restrict__ sRow,
                                                float* __restrict__ sCol) {
    int b = blockIdx.y, which = blockIdx.z;
    int i = blockIdx.x * 256 + threadIdx.x;
    const float* p = which ? sColp : sRowp;
    float s = 0.f;
#pragma unroll
    for (int k = 0; k < 32; ++k) s += p[((size_t)(b * 32 + k)) * 2048 + i];
    (which ? sCol : sRow)[b * 2048 + i] = s;
}

// ---------- 614-th smallest via binary search on float bits ----------
__global__ __launch_bounds__(64) void select_k(const float* __restrict__ sRow,
                                               const float* __restrict__ sCol,
                                               float* __restrict__ rth,
                                               float* __restrict__ cth) {
    int kind = blockIdx.x, b = blockIdx.y, t = threadIdx.x;
    const float* vals = (kind == 0) ? (sRow + b * NN) : (sCol + b * MM);
    float v[32];
#pragma unroll
    for (int i = 0; i < 32; ++i) v[i] = vals[t + (i << 6)];
    unsigned lo = 0u, hi = 0x7F800000u;
    while (lo < hi) {
        unsigned mid = lo + ((hi - lo) >> 1);
        float pv = __uint_as_float(mid);
        int c = 0;
#pragma unroll
        for (int i = 0; i < 32; ++i) c += (v[i] <= pv) ? 1 : 0;
#pragma unroll
        for (int off = 32; off > 0; off >>= 1) c += __shfl_down(c, off);
        c = __shfl(c, 0);
        if (c >= KSEL + 1) hi = mid; else lo = mid + 1;
    }
    if (t == 0) { if (kind == 0) rth[b] = __uint_as_float(lo); else cth[b] = __uint_as_float(lo); }
}

// ---------- masks + src_weight ----------
__global__ __launch_bounds__(256) void masks_k(const float* __restrict__ sRow,
                                               const float* __restrict__ sCol,
                                               const float* __restrict__ rth,
                                               const float* __restrict__ cth,
                                               float* __restrict__ out) {
    int b = blockIdx.x, t = threadIdx.x;
    float r = rth[b], c = cth[b];
    int cnt = 0;
    bool ms[8];
#pragma unroll
    for (int i = 0; i < 8; ++i) {
        int n = t + (i << 8);
        ms[i] = sRow[b * NN + n] < r;
        out[OUT_MS + b * NN + n] = ms[i] ? 1.f : 0.f;
        out[OUT_MT + b * MM + n] = (sCol[b * MM + n] < c) ? 1.f : 0.f;
        cnt += ms[i] ? 0 : 1;
    }
#pragma unroll
    for (int off = 32; off > 0; off >>= 1) cnt += __shfl_down(cnt, off);
    __shared__ int wcnt[4];
    int wave = t >> 6, lane = t & 63;
    if (lane == 0) wcnt[wave] = cnt;
    __syncthreads();
    float inv = 1.f / (float)(wcnt[0] + wcnt[1] + wcnt[2] + wcnt[3]);
#pragma unroll
    for (int i = 0; i < 8; ++i) {
        int n = t + (i << 8);
        out[OUT_W + b * NN + n] = ms[i] ? 0.f : inv;
    }
}

// ---------- combine corr partials -> src_corr ----------
__global__ __launch_bounds__(256) void comb_corr_k(const float* __restrict__ csP,
                                                   const float* __restrict__ d0P,
                                                   const float* __restrict__ d1P,
                                                   const float* __restrict__ d2P,
                                                   float* __restrict__ out) {
    int b = blockIdx.y;
    int n = blockIdx.x * 256 + threadIdx.x;
    float cs = 0.f, e0 = 0.f, e1 = 0.f, e2 = 0.f;
#pragma unroll
    for (int k = 0; k < 32; ++k) {
        size_t o = ((size_t)(b * 32 + k)) * NN + n;
        cs += csP[o]; e0 += d0P[o]; e1 += d1P[o]; e2 += d2P[o];
    }
    cs = (cs < 1e-5f) ? 1e-5f : cs;
    out[((size_t)(b * 3 + 0)) * NN + n] = e0 / cs;
    out[((size_t)(b * 3 + 1)) * NN + n] = e1 / cs;
    out[((size_t)(b * 3 + 2)) * NN + n] = e2 / cs;
}

extern "C" void kernel_launch(void* const* d_in, const int* in_sizes, int n_in,
                              void* d_out, int out_size, void* d_ws, size_t ws_size,
                              hipStream_t stream) {
    const float* src_emb = (const float*)d_in[0];
    const float* tgt_emb = (const float*)d_in[1];
    const float* tgt = (const float*)d_in[3];
    float* out = (float*)d_out;

    unsigned short* us = (unsigned short*)d_ws;
    const size_t TSZ = (size_t)BB * NN * 64;
    unsigned short* A0 = us;
    unsigned short* A1 = A0 + TSZ;
    unsigned short* A2 = A1 + TSZ;
    unsigned short* B0 = A2 + TSZ;
    unsigned short* B1 = B0 + TSZ;
    unsigned short* B2 = B1 + TSZ;
    float* f = (float*)(B2 + TSZ);
    const size_t P = (size_t)BB * 32 * NN;
    float* rpM = f;            f += P;
    float* rpS = f;            f += P;
    int*   rpI = (int*)f;      f += P;
    float* rpM2 = f;           f += P;
    int*   rpI2 = (int*)f;     f += P;
    float* cpM = f;            f += P;
    float* cpS = f;            f += P;
    float* sRowp = f;          f += P;
    float* sColp = f;          f += P;
    float* csP = f;            f += P;
    float* d0P = f;            f += P;
    float* d1P = f;            f += P;
    float* d2P = f;            f += P;
    float* xx = f;             f += BB * NN;
    float* yy = f;             f += BB * MM;
    float* rowmax = f;         f += BB * NN;
    float* rowsum = f;         f += BB * NN;
    int*   rowamax = (int*)f;  f += BB * NN;
    int*   rowI1 = (int*)f;    f += BB * NN;
    int*   rowI2 = (int*)f;    f += BB * NN;
    float* colmax = f;         f += BB * MM;
    float* colsum = f;         f += BB * MM;
    float* sRow = f;           f += BB * NN;
    float* sCol = f;           f += BB * MM;
    float* rth = f;            f += BB;
    float* cth = f;            f += BB;

    split_k<<<dim3(NN / 64, BB), 256, 0, stream>>>(src_emb, A0, A1, A2, xx);
    split_k<<<dim3(MM / 64, BB), 256, 0, stream>>>(tgt_emb, B0, B1, B2, yy);
    pass1_k<<<dim3(MM / 128, NN / 128, BB), 256, 0, stream>>>(A0, A1, A2, B0, B1, B2, xx, yy,
                                                              rpM, rpS, rpI, rpM2, rpI2, cpM, cpS);
    comb_row_k<<<dim3(NN / 256, BB), 256, 0, stream>>>(rpM, rpS, rpI, rpM2, rpI2,
                                                       rowmax, rowsum, rowI1, rowI2);
    comb_col_k<<<dim3(MM / 256, BB), 256, 0, stream>>>(cpM, cpS, colmax, colsum);
    fix_k<<<dim3(NN / 256, BB), 256, 0, stream>>>(src_emb, tgt_emb, yy, rowI1, rowI2, rowamax);
    pass2_k<<<dim3(MM / 128, NN / 128, BB), 256, 0, stream>>>(A0, A1, A2, B0, B1, B2, xx, yy,
                                                              rowmax, rowsum, colmax, colsum,
                                                              sRowp, sColp);
    comb_s_k<<<dim3(2048 / 256, BB, 2), 256, 0, stream>>>(sRowp, sColp, sRow, sCol);
    select_k<<<dim3(2, BB), 64, 0, stream>>>(sRow, sCol, rth, cth);
    masks_k<<<dim3(BB), 256, 0, stream>>>(sRow, sCol, rth, cth, out);
    pass3_k<<<dim3(MM / 128, NN / 128, BB), 256, 0, stream>>>(A0, A1, B0, B1, xx, yy,
                                                              rowmax, rowsum, rowamax, sRow, sCol,
                                                              rth, cth, tgt, csP, d0P, d1P, d2P);
    comb_corr_k<<<dim3(NN / 256, BB), 256, 0, stream>>>(csP, d0P, d1P, d2P, out);
}

// Round 7
// 319.038 us; speedup vs baseline: 1.3918x; 1.1573x over previous
//
#include <hip/hip_runtime.h>

// EPCOR eval path on MI355X — MFMA recompute, swizzled operands, orientation-
// matched epilogues. pd never materialized. Row-argmax rescued exactly in fp32.
#define BB 8
#define CC 64
#define NN 2048
#define MM 2048
#define KSEL 613            // 0-based index of the 614-th smallest (int(2048*0.3)=614)
#define TSZ ((size_t)(2048 * 64))   // elements per batch per operand array

// Output layout (floats): src_corr [B,3,N] | src_weight [B,N] | mask_src [B,N] | mask_tgt [B,M]
#define OUT_W  (BB * 3 * NN)
#define OUT_MS (OUT_W + BB * NN)
#define OUT_MT (OUT_MS + BB * NN)

typedef unsigned short us;
typedef __attribute__((ext_vector_type(8))) short v8s;
typedef __attribute__((ext_vector_type(4))) float v4f;

static __device__ inline us f2bf(float x) {
    union { float f; unsigned u; } v; v.f = x;
    unsigned r = v.u + 0x7FFF + ((v.u >> 16) & 1);
    return (us)(r >> 16);
}
static __device__ inline float bf2f(us h) {
    union { float f; unsigned u; } v; v.u = ((unsigned)h) << 16; return v.f;
}

// ---------- split: fp32 [B,64,L] -> 3 swizzled bf16 operand arrays + sq-norms ----------
// swizzle: elem(n,c) at (n>>4)*1024 + (c>>5)*512 + ((c>>3)&3)*128 + (n&15)*8 + (c&7)
// -> a wave fragment load (16 rows x 8 k, 4 quads) is one contiguous 1KB dwordx4.
__global__ __launch_bounds__(256) void split_k(const float* __restrict__ in,
                                               us* __restrict__ T0, us* __restrict__ T1,
                                               us* __restrict__ T2, float* __restrict__ nrm) {
    __shared__ float tile[64][64];  // [c][n]
    __shared__ float xs[64][4];
    int b = blockIdx.y, n0 = blockIdx.x << 6, t = threadIdx.x;
    int c4 = t >> 6, nl = t & 63;
#pragma unroll
    for (int r = 0; r < 16; ++r) {
        int c = (r << 2) + c4;
        tile[c][nl] = in[((size_t)(b * CC + c)) * NN + n0 + nl];
    }
    __syncthreads();
    int n = t >> 2, cq = t & 3;
    us h0[16], h1[16], h2[16];
    float ss = 0.f;
#pragma unroll
    for (int j = 0; j < 16; ++j) {
        float a = tile[cq * 16 + j][n];
        ss += a * a;
        h0[j] = f2bf(a);
        float r1 = a - bf2f(h0[j]);
        h1[j] = f2bf(r1);
        float r2 = r1 - bf2f(h1[j]);
        h2[j] = f2bf(r2);
    }
    xs[n][cq] = ss;
    size_t base = (size_t)b * TSZ + (size_t)((n0 + n) >> 4) * 1024
                + (size_t)(cq >> 1) * 512 + (size_t)((cq << 1) & 3) * 128 + (size_t)(n & 15) * 8;
    *(v8s*)(T0 + base) = *(v8s*)h0;       *(v8s*)(T0 + base + 128) = *(v8s*)(h0 + 8);
    *(v8s*)(T1 + base) = *(v8s*)h1;       *(v8s*)(T1 + base + 128) = *(v8s*)(h1 + 8);
    *(v8s*)(T2 + base) = *(v8s*)h2;       *(v8s*)(T2 + base + 128) = *(v8s*)(h2 + 8);
    __syncthreads();
    if (t < 64) nrm[b * NN + n0 + t] = xs[t][0] + xs[t][1] + xs[t][2] + xs[t][3];
}

// ---------- 6-term mainloop, swizzled coalesced fragment loads ----------
__device__ inline void gemm6(const us* __restrict__ A0, const us* __restrict__ A1,
                             const us* __restrict__ A2, const us* __restrict__ B0,
                             const us* __restrict__ B1, const us* __restrict__ B2,
                             int b, int n0, int m0, int l15, int quad, v4f acc[4][4]) {
    size_t bb = (size_t)b * TSZ;
#pragma unroll
    for (int ks = 0; ks < 2; ++ks) {
        size_t ra[4], rb[4];
#pragma unroll
        for (int q = 0; q < 4; ++q) {
            ra[q] = bb + (size_t)((n0 >> 4) + q) * 1024 + ks * 512 + quad * 128 + l15 * 8;
            rb[q] = bb + (size_t)((m0 >> 4) + q) * 1024 + ks * 512 + quad * 128 + l15 * 8;
        }
        v8s a0f[4], a1f[4], a2f[4], b0f[4], b1f[4], b2f[4];
#pragma unroll
        for (int q = 0; q < 4; ++q) { a0f[q] = *(const v8s*)(A0 + ra[q]); b0f[q] = *(const v8s*)(B0 + rb[q]); }
#pragma unroll
        for (int nt = 0; nt < 4; ++nt)
#pragma unroll
            for (int mt = 0; mt < 4; ++mt)
                acc[nt][mt] = __builtin_amdgcn_mfma_f32_16x16x32_bf16(a0f[nt], b0f[mt], acc[nt][mt], 0, 0, 0);
#pragma unroll
        for (int q = 0; q < 4; ++q) b1f[q] = *(const v8s*)(B1 + rb[q]);
#pragma unroll
        for (int nt = 0; nt < 4; ++nt)
#pragma unroll
            for (int mt = 0; mt < 4; ++mt)
                acc[nt][mt] = __builtin_amdgcn_mfma_f32_16x16x32_bf16(a0f[nt], b1f[mt], acc[nt][mt], 0, 0, 0);
#pragma unroll
        for (int q = 0; q < 4; ++q) b2f[q] = *(const v8s*)(B2 + rb[q]);
#pragma unroll
        for (int nt = 0; nt < 4; ++nt)
#pragma unroll
            for (int mt = 0; mt < 4; ++mt)
                acc[nt][mt] = __builtin_amdgcn_mfma_f32_16x16x32_bf16(a0f[nt], b2f[mt], acc[nt][mt], 0, 0, 0);
#pragma unroll
        for (int q = 0; q < 4; ++q) a1f[q] = *(const v8s*)(A1 + ra[q]);
#pragma unroll
        for (int nt = 0; nt < 4; ++nt)
#pragma unroll
            for (int mt = 0; mt < 4; ++mt)
                acc[nt][mt] = __builtin_amdgcn_mfma_f32_16x16x32_bf16(a1f[nt], b0f[mt], acc[nt][mt], 0, 0, 0);
#pragma unroll
        for (int nt = 0; nt < 4; ++nt)
#pragma unroll
            for (int mt = 0; mt < 4; ++mt)
                acc[nt][mt] = __builtin_amdgcn_mfma_f32_16x16x32_bf16(a1f[nt], b1f[mt], acc[nt][mt], 0, 0, 0);
#pragma unroll
        for (int q = 0; q < 4; ++q) a2f[q] = *(const v8s*)(A2 + ra[q]);
#pragma unroll
        for (int nt = 0; nt < 4; ++nt)
#pragma unroll
            for (int mt = 0; mt < 4; ++mt)
                acc[nt][mt] = __builtin_amdgcn_mfma_f32_16x16x32_bf16(a2f[nt], b0f[mt], acc[nt][mt], 0, 0, 0);
    }
}

// ---------- 3-term mainloop (corr): a0b0 + a0b1 + a1b0 ----------
__device__ inline void gemm3(const us* __restrict__ A0, const us* __restrict__ A1,
                             const us* __restrict__ B0, const us* __restrict__ B1,
                             int b, int n0, int m0, int l15, int quad, v4f acc[4][4]) {
    size_t bb = (size_t)b * TSZ;
#pragma unroll
    for (int ks = 0; ks < 2; ++ks) {
        size_t ra[4], rb[4];
#pragma unroll
        for (int q = 0; q < 4; ++q) {
            ra[q] = bb + (size_t)((n0 >> 4) + q) * 1024 + ks * 512 + quad * 128 + l15 * 8;
            rb[q] = bb + (size_t)((m0 >> 4) + q) * 1024 + ks * 512 + quad * 128 + l15 * 8;
        }
        v8s a0f[4], a1f[4], b0f[4], b1f[4];
#pragma unroll
        for (int q = 0; q < 4; ++q) { a0f[q] = *(const v8s*)(A0 + ra[q]); b0f[q] = *(const v8s*)(B0 + rb[q]); }
#pragma unroll
        for (int nt = 0; nt < 4; ++nt)
#pragma unroll
            for (int mt = 0; mt < 4; ++mt)
                acc[nt][mt] = __builtin_amdgcn_mfma_f32_16x16x32_bf16(a0f[nt], b0f[mt], acc[nt][mt], 0, 0, 0);
#pragma unroll
        for (int q = 0; q < 4; ++q) b1f[q] = *(const v8s*)(B1 + rb[q]);
#pragma unroll
        for (int nt = 0; nt < 4; ++nt)
#pragma unroll
            for (int mt = 0; mt < 4; ++mt)
                acc[nt][mt] = __builtin_amdgcn_mfma_f32_16x16x32_bf16(a0f[nt], b1f[mt], acc[nt][mt], 0, 0, 0);
#pragma unroll
        for (int q = 0; q < 4; ++q) a1f[q] = *(const v8s*)(A1 + ra[q]);
#pragma unroll
        for (int nt = 0; nt < 4; ++nt)
#pragma unroll
            for (int mt = 0; mt < 4; ++mt)
                acc[nt][mt] = __builtin_amdgcn_mfma_f32_16x16x32_bf16(a1f[nt], b0f[mt], acc[nt][mt], 0, 0, 0);
    }
}

#define IDS \
    int t = threadIdx.x; int lane = t & 63; int wave = t >> 6; \
    int wx = wave & 1, wy = wave >> 1; \
    int l15 = lane & 15, quad = lane >> 4; \
    int b = blockIdx.z;

// ---------- rstat: SWAPPED gemm -> per-row top-2/max/sumexp in w-space (w = pd + xx[n]) ----------
// grid (m-tiles 16, n-tiles 16, B). acc[it][jt]: m = m0+it*16+quad*4+r, n = n0+jt*16+l15.
__global__ __launch_bounds__(256, 3) void rstat_k(const us* __restrict__ TB0, const us* __restrict__ TB1,
                                                  const us* __restrict__ TB2, const us* __restrict__ TA0,
                                                  const us* __restrict__ TA1, const us* __restrict__ TA2,
                                                  const float* __restrict__ yy,
                                                  float* __restrict__ rpM, float* __restrict__ rpS,
                                                  int* __restrict__ rpI,
                                                  float* __restrict__ rpM2, int* __restrict__ rpI2) {
    IDS
    int m0 = blockIdx.x * 128 + wx * 64;
    int n0 = blockIdx.y * 128 + wy * 64;
    v4f acc[4][4];
#pragma unroll
    for (int i = 0; i < 4; ++i)
#pragma unroll
        for (int j = 0; j < 4; ++j) acc[i][j] = (v4f){0.f, 0.f, 0.f, 0.f};
    gemm6(TB0, TB1, TB2, TA0, TA1, TA2, b, m0, n0, l15, quad, acc);
    float ym[4][4];
#pragma unroll
    for (int it = 0; it < 4; ++it)
#pragma unroll
        for (int r = 0; r < 4; ++r) ym[it][r] = yy[b * MM + m0 + it * 16 + quad * 4 + r];
#pragma unroll
    for (int jt = 0; jt < 4; ++jt) {
        float w[16];
#pragma unroll
        for (int it = 0; it < 4; ++it)
#pragma unroll
            for (int r = 0; r < 4; ++r) w[it * 4 + r] = 2.f * acc[it][jt][r] - ym[it][r];
        float v1 = w[0]; int i1 = quad * 4;
        float v2 = -3.4e38f; int i2 = quad * 4;
#pragma unroll
        for (int k = 1; k < 16; ++k) {
            int ml = (k >> 2) * 16 + quad * 4 + (k & 3);
            if (w[k] > v1) { v2 = v1; i2 = i1; v1 = w[k]; i1 = ml; }
            else if (w[k] > v2) { v2 = w[k]; i2 = ml; }
        }
        float S = 0.f;
#pragma unroll
        for (int k = 0; k < 16; ++k) S += __expf(w[k] - v1);
#pragma unroll
        for (int d = 16; d <= 32; d <<= 1) {
            float oV1 = __shfl_xor(v1, d); float oS = __shfl_xor(S, d);
            int oi1 = __shfl_xor(i1, d);
            float oV2 = __shfl_xor(v2, d); int oi2 = __shfl_xor(i2, d);
            float nM = fmaxf(v1, oV1);
            S = S * __expf(v1 - nM) + oS * __expf(oV1 - nM);
            if (oV1 > v1) {
                if (v1 > oV2) { v2 = v1; i2 = i1; } else { v2 = oV2; i2 = oi2; }
                v1 = oV1; i1 = oi1;
            } else if (oV1 > v2) { v2 = oV1; i2 = oi1; }
        }
        if (quad == 0) {
            int n = n0 + jt * 16 + l15;
            size_t o = ((size_t)(b * 32 + 2 * blockIdx.x + wx)) * NN + n;
            rpM[o] = v1; rpS[o] = S; rpI[o] = m0 + i1; rpM2[o] = v2; rpI2[o] = m0 + i2;
        }
    }
}

// ---------- comb_rowfix: merge row partials + exact-fp32 argmax rescue ----------
// writes rpx = rowmax + xx (w-space max), rinv = 1/rowsum, rowamax.
__global__ __launch_bounds__(256) void comb_rowfix_k(const float* __restrict__ rpM,
                                                     const float* __restrict__ rpS,
                                                     const int* __restrict__ rpI,
                                                     const float* __restrict__ rpM2,
                                                     const int* __restrict__ rpI2,
                                                     const float* __restrict__ src_emb,
                                                     const float* __restrict__ tgt_emb,
                                                     const float* __restrict__ yy,
                                                     float* __restrict__ rpx, float* __restrict__ rinv,
                                                     int* __restrict__ rowamax) {
    int b = blockIdx.y;
    int n = blockIdx.x * 256 + threadIdx.x;
    float V1 = -3.4e38f, V2 = -3.4e38f; int I1 = 0, I2 = 0;
#pragma unroll
    for (int k = 0; k < 32; ++k) {
        size_t o = ((size_t)(b * 32 + k)) * NN + n;
        float w1 = rpM[o], w2 = rpM2[o]; int j1 = rpI[o], j2 = rpI2[o];
        if (w1 > V1) {
            if (V1 > w2) { V2 = V1; I2 = I1; } else { V2 = w2; I2 = j2; }
            V1 = w1; I1 = j1;
        } else if (w1 > V2) { V2 = w1; I2 = j1; }
    }
    float S = 0.f;
#pragma unroll
    for (int k = 0; k < 32; ++k) {
        size_t o = ((size_t)(b * 32 + k)) * NN + n;
        S += rpS[o] * __expf(rpM[o] - V1);
    }
    rpx[b * NN + n] = V1;
    rinv[b * NN + n] = 1.f / S;
    // exact rescue among {I1, I2}
    const float* Sp = src_emb + (size_t)b * CC * NN;
    const float* Tp = tgt_emb + (size_t)b * CC * MM;
    float d1 = 0.f, d2 = 0.f;
#pragma unroll
    for (int c = 0; c < CC; ++c) {
        float s = Sp[(size_t)c * NN + n];
        d1 += s * Tp[(size_t)c * MM + I1];
        d2 += s * Tp[(size_t)c * MM + I2];
    }
    float p1 = 2.f * d1 - yy[b * MM + I1];
    float p2 = 2.f * d2 - yy[b * MM + I2];
    int best;
    if (p2 > p1) best = I2;
    else if (p1 > p2) best = I1;
    else best = (I1 < I2) ? I1 : I2;
    rowamax[b * NN + n] = best;
}

// ---------- cstat_scol: NORMAL gemm -> col stats (w' = pd + yy[m] space) AND sCol partials ----------
// grid (m-tiles 16, n-tiles 16, B). acc[nt][mt]: n = n0+nt*16+quad*4+r, m = m0+mt*16+l15.
__global__ __launch_bounds__(256, 3) void cstat_scol_k(const us* __restrict__ TA0, const us* __restrict__ TA1,
                                                       const us* __restrict__ TA2, const us* __restrict__ TB0,
                                                       const us* __restrict__ TB1, const us* __restrict__ TB2,
                                                       const float* __restrict__ xx,
                                                       const float* __restrict__ yy,
                                                       const float* __restrict__ rpx,
                                                       const float* __restrict__ rinv,
                                                       float* __restrict__ cpM, float* __restrict__ cpS,
                                                       float* __restrict__ sColp) {
    IDS
    int m0 = blockIdx.x * 128 + wx * 64;
    int n0 = blockIdx.y * 128 + wy * 64;
    v4f acc[4][4];
#pragma unroll
    for (int i = 0; i < 4; ++i)
#pragma unroll
        for (int j = 0; j < 4; ++j) acc[i][j] = (v4f){0.f, 0.f, 0.f, 0.f};
    gemm6(TA0, TA1, TA2, TB0, TB1, TB2, b, n0, m0, l15, quad, acc);
    float xm[4][4], rpxv[4][4], rinvv[4][4];
#pragma unroll
    for (int nt = 0; nt < 4; ++nt)
#pragma unroll
        for (int r = 0; r < 4; ++r) {
            int n = n0 + nt * 16 + quad * 4 + r;
            xm[nt][r] = xx[b * NN + n];
            rpxv[nt][r] = rpx[b * NN + n];
            rinvv[nt][r] = rinv[b * NN + n];
        }
    float yv[4];
#pragma unroll
    for (int mt = 0; mt < 4; ++mt) yv[mt] = yy[b * MM + m0 + mt * 16 + l15];
#pragma unroll
    for (int mt = 0; mt < 4; ++mt) {
        float cm = -3.4e38f;
#pragma unroll
        for (int nt = 0; nt < 4; ++nt)
#pragma unroll
            for (int r = 0; r < 4; ++r)
                cm = fmaxf(cm, 2.f * acc[nt][mt][r] - xm[nt][r]);
        cm = fmaxf(cm, __shfl_xor(cm, 16));
        cm = fmaxf(cm, __shfl_xor(cm, 32));
        float cs = 0.f, sc = 0.f;
#pragma unroll
        for (int nt = 0; nt < 4; ++nt)
#pragma unroll
            for (int r = 0; r < 4; ++r) {
                float a2 = 2.f * acc[nt][mt][r];
                cs += __expf(a2 - xm[nt][r] - cm);
                sc += __expf(a2 - yv[mt] - rpxv[nt][r]) * rinvv[nt][r];
            }
        cs += __shfl_xor(cs, 16); cs += __shfl_xor(cs, 32);
        sc += __shfl_xor(sc, 16); sc += __shfl_xor(sc, 32);
        if (quad == 0) {
            size_t o = ((size_t)(b * 32 + 2 * blockIdx.y + wy)) * MM + m0 + mt * 16 + l15;
            cpM[o] = cm; cpS[o] = cs; sColp[o] = sc;
        }
    }
}

// ---------- comb_colscol: merge col partials -> dmx = colmax+yy, cinv = 1/colsum; sum sCol ----------
__global__ __launch_bounds__(256) void comb_colscol_k(const float* __restrict__ cpM,
                                                      const float* __restrict__ cpS,
                                                      const float* __restrict__ sColp,
                                                      float* __restrict__ dmx, float* __restrict__ cinv,
                                                      float* __restrict__ sCol) {
    int b = blockIdx.y;
    int m = blockIdx.x * 256 + threadIdx.x;
    float M = -3.4e38f;
#pragma unroll
    for (int k = 0; k < 32; ++k) M = fmaxf(M, cpM[((size_t)(b * 32 + k)) * MM + m]);
    float S = 0.f, C = 0.f;
#pragma unroll
    for (int k = 0; k < 32; ++k) {
        size_t o = ((size_t)(b * 32 + k)) * MM + m;
        S += cpS[o] * __expf(cpM[o] - M);
        C += sColp[o];
    }
    dmx[b * MM + m] = M;
    cinv[b * MM + m] = 1.f / S;
    sCol[b * MM + m] = C;
}

// ---------- srow: SWAPPED gemm -> sRow partials ----------
__global__ __launch_bounds__(256, 3) void srow_k(const us* __restrict__ TB0, const us* __restrict__ TB1,
                                                 const us* __restrict__ TB2, const us* __restrict__ TA0,
                                                 const us* __restrict__ TA1, const us* __restrict__ TA2,
                                                 const float* __restrict__ xx,
                                                 const float* __restrict__ dmx,
                                                 const float* __restrict__ cinv,
                                                 float* __restrict__ sRowp) {
    IDS
    int m0 = blockIdx.x * 128 + wx * 64;
    int n0 = blockIdx.y * 128 + wy * 64;
    v4f acc[4][4];
#pragma unroll
    for (int i = 0; i < 4; ++i)
#pragma unroll
        for (int j = 0; j < 4; ++j) acc[i][j] = (v4f){0.f, 0.f, 0.f, 0.f};
    gemm6(TB0, TB1, TB2, TA0, TA1, TA2, b, m0, n0, l15, quad, acc);
    float dmv[4][4], civ[4][4];
#pragma unroll
    for (int it = 0; it < 4; ++it)
#pragma unroll
        for (int r = 0; r < 4; ++r) {
            int m = m0 + it * 16 + quad * 4 + r;
            dmv[it][r] = dmx[b * MM + m];
            civ[it][r] = cinv[b * MM + m];
        }
#pragma unroll
    for (int jt = 0; jt < 4; ++jt) {
        float xv = xx[b * NN + n0 + jt * 16 + l15];
        float s = 0.f;
#pragma unroll
        for (int it = 0; it < 4; ++it)
#pragma unroll
            for (int r = 0; r < 4; ++r)
                s += __expf(2.f * acc[it][jt][r] - xv - dmv[it][r]) * civ[it][r];
        s += __shfl_xor(s, 16);
        s += __shfl_xor(s, 32);
        if (quad == 0)
            sRowp[((size_t)(b * 32 + 2 * blockIdx.x + wx)) * NN + n0 + jt * 16 + l15] = s;
    }
}

// ---------- comb_srow: sum sRow partials ----------
__global__ __launch_bounds__(256) void comb_srow_k(const float* __restrict__ sRowp,
                                                   float* __restrict__ sRow) {
    int b = blockIdx.y;
    int n = blockIdx.x * 256 + threadIdx.x;
    float s = 0.f;
#pragma unroll
    for (int k = 0; k < 32; ++k) s += sRowp[((size_t)(b * 32 + k)) * NN + n];
    sRow[b * NN + n] = s;
}

// ---------- selmask: thresholds (614-th smallest, binary search) + masks + src_weight ----------
__global__ __launch_bounds__(256) void selmask_k(const float* __restrict__ sRow,
                                                 const float* __restrict__ sCol,
                                                 float* __restrict__ out) {
    __shared__ float th[2];
    __shared__ int wcnt[4];
    int b = blockIdx.x, t = threadIdx.x;
    int lane = t & 63, wv = t >> 6;
    if (wv < 2) {
        const float* vals = (wv == 0) ? (sRow + b * NN) : (sCol + b * MM);
        float v[32];
#pragma unroll
        for (int i = 0; i < 32; ++i) v[i] = vals[lane + (i << 6)];
        unsigned lo = 0u, hi = 0x7F800000u;
        while (lo < hi) {
            unsigned mid = lo + ((hi - lo) >> 1);
            float pv = __uint_as_float(mid);
            int c = 0;
#pragma unroll
            for (int i = 0; i < 32; ++i) c += (v[i] <= pv) ? 1 : 0;
#pragma unroll
            for (int off = 32; off > 0; off >>= 1) c += __shfl_down(c, off);
            c = __shfl(c, 0);
            if (c >= KSEL + 1) hi = mid; else lo = mid + 1;
        }
        if (lane == 0) th[wv] = __uint_as_float(lo);
    }
    __syncthreads();
    float r = th[0], c = th[1];
    int cnt = 0;
    bool ms[8];
#pragma unroll
    for (int i = 0; i < 8; ++i) {
        int n = t + (i << 8);
        ms[i] = sRow[b * NN + n] < r;
        out[OUT_MS + b * NN + n] = ms[i] ? 1.f : 0.f;
        out[OUT_MT + b * MM + n] = (sCol[b * MM + n] < c) ? 1.f : 0.f;
        cnt += ms[i] ? 0 : 1;
    }
#pragma unroll
    for (int off = 32; off > 0; off >>= 1) cnt += __shfl_down(cnt, off);
    if (lane == 0) wcnt[wv] = cnt;
    __syncthreads();
    float inv = 1.f / (float)(wcnt[0] + wcnt[1] + wcnt[2] + wcnt[3]);
#pragma unroll
    for (int i = 0; i < 8; ++i) {
        int n = t + (i << 8);
        out[OUT_W + b * NN + n] = ms[i] ? 0.f : inv;
    }
}

// ---------- pass3: corr partials (3-term GEMM, normal orientation) ----------
__global__ __launch_bounds__(256, 3) void pass3_k(const us* __restrict__ TA0, const us* __restrict__ TA1,
                                                  const us* __restrict__ TB0, const us* __restrict__ TB1,
                                                  const float* __restrict__ yy,
                                                  const float* __restrict__ rpx,
                                                  const float* __restrict__ rinv,
                                                  const int* __restrict__ rowamax,
                                                  const float* __restrict__ out,   // mask flags
                                                  const float* __restrict__ tgt,
                                                  float* __restrict__ csP, float* __restrict__ d0P,
                                                  float* __restrict__ d1P, float* __restrict__ d2P) {
    IDS
    int m0 = blockIdx.x * 128 + wx * 64;
    int n0 = blockIdx.y * 128 + wy * 64;
    v4f acc[4][4];
#pragma unroll
    for (int i = 0; i < 4; ++i)
#pragma unroll
        for (int j = 0; j < 4; ++j) acc[i][j] = (v4f){0.f, 0.f, 0.f, 0.f};
    gemm3(TA0, TA1, TB0, TB1, b, n0, m0, l15, quad, acc);
    float yv[4], t0[4], t1[4], t2[4]; bool mtgt[4]; int mg[4];
#pragma unroll
    for (int mt = 0; mt < 4; ++mt) {
        int m = m0 + mt * 16 + l15;
        mg[mt] = m;
        yv[mt] = yy[b * MM + m];
        mtgt[mt] = out[OUT_MT + b * MM + m] != 0.f;
        t0[mt] = tgt[((size_t)(b * 3 + 0)) * MM + m];
        t1[mt] = tgt[((size_t)(b * 3 + 1)) * MM + m];
        t2[mt] = tgt[((size_t)(b * 3 + 2)) * MM + m];
    }
#pragma unroll
    for (int nt = 0; nt < 4; ++nt) {
        float cs[4], e0[4], e1[4], e2[4];
#pragma unroll
        for (int r = 0; r < 4; ++r) {
            int n = n0 + nt * 16 + quad * 4 + r;
            float rpxn = rpx[b * NN + n];
            float rinn = rinv[b * NN + n];
            int kidx = rowamax[b * NN + n];
            bool ms = out[OUT_MS + b * NN + n] != 0.f;
            float a = 0.f, b0v = 0.f, b1v = 0.f, b2v = 0.f;
#pragma unroll
            for (int mt = 0; mt < 4; ++mt) {
                bool keep = ms || mtgt[mt] || (mg[mt] == kidx);
                if (keep) {
                    float s = __expf(2.f * acc[nt][mt][r] - yv[mt] - rpxn) * rinn;
                    a += s; b0v += s * t0[mt]; b1v += s * t1[mt]; b2v += s * t2[mt];
                }
            }
            cs[r] = a; e0[r] = b0v; e1[r] = b1v; e2[r] = b2v;
        }
#pragma unroll
        for (int d = 1; d < 16; d <<= 1)
#pragma unroll
            for (int r = 0; r < 4; ++r) {
                cs[r] += __shfl_xor(cs[r], d);
                e0[r] += __shfl_xor(e0[r], d);
                e1[r] += __shfl_xor(e1[r], d);
                e2[r] += __shfl_xor(e2[r], d);
            }
        if (l15 == 0) {
            size_t o = ((size_t)(b * 32 + 2 * blockIdx.x + wx)) * NN + n0 + nt * 16 + quad * 4;
            *(float4*)&csP[o] = make_float4(cs[0], cs[1], cs[2], cs[3]);
            *(float4*)&d0P[o] = make_float4(e0[0], e0[1], e0[2], e0[3]);
            *(float4*)&d1P[o] = make_float4(e1[0], e1[1], e1[2], e1[3]);
            *(float4*)&d2P[o] = make_float4(e2[0], e2[1], e2[2], e2[3]);
        }
    }
}

// ---------- comb_corr: combine corr partials -> src_corr ----------
__global__ __launch_bounds__(256) void comb_corr_k(const float* __restrict__ csP,
                                                   const float* __restrict__ d0P,
                                                   const float* __restrict__ d1P,
                                                   const float* __restrict__ d2P,
                                                   float* __restrict__ out) {
    int b = blockIdx.y;
    int n = blockIdx.x * 256 + threadIdx.x;
    float cs = 0.f, e0 = 0.f, e1 = 0.f, e2 = 0.f;
#pragma unroll
    for (int k = 0; k < 32; ++k) {
        size_t o = ((size_t)(b * 32 + k)) * NN + n;
        cs += csP[o]; e0 += d0P[o]; e1 += d1P[o]; e2 += d2P[o];
    }
    cs = (cs < 1e-5f) ? 1e-5f : cs;
    out[((size_t)(b * 3 + 0)) * NN + n] = e0 / cs;
    out[((size_t)(b * 3 + 1)) * NN + n] = e1 / cs;
    out[((size_t)(b * 3 + 2)) * NN + n] = e2 / cs;
}

extern "C" void kernel_launch(void* const* d_in, const int* in_sizes, int n_in,
                              void* d_out, int out_size, void* d_ws, size_t ws_size,
                              hipStream_t stream) {
    const float* src_emb = (const float*)d_in[0];
    const float* tgt_emb = (const float*)d_in[1];
    const float* tgt = (const float*)d_in[3];
    float* out = (float*)d_out;

    us* u = (us*)d_ws;
    us* TA0 = u;             us* TA1 = TA0 + BB * TSZ;  us* TA2 = TA1 + BB * TSZ;
    us* TB0 = TA2 + BB * TSZ; us* TB1 = TB0 + BB * TSZ; us* TB2 = TB1 + BB * TSZ;
    float* f = (float*)(TB2 + BB * TSZ);
    const size_t P = (size_t)BB * 32 * NN;
    float* rpM = f;        f += P;
    float* rpS = f;        f += P;
    int*   rpI = (int*)f;  f += P;
    float* rpM2 = f;       f += P;
    int*   rpI2 = (int*)f; f += P;
    float* cpM = f;        f += P;
    float* cpS = f;        f += P;
    float* sColp = f;      f += P;
    float* sRowp = f;      f += P;
    float* csP = f;        f += P;
    float* d0P = f;        f += P;
    float* d1P = f;        f += P;
    float* d2P = f;        f += P;
    float* xx = f;         f += BB * NN;
    float* yy = f;         f += BB * MM;
    float* rpx = f;        f += BB * NN;
    float* rinv = f;       f += BB * NN;
    int*   rowamax = (int*)f; f += BB * NN;
    float* dmx = f;        f += BB * MM;
    float* cinv = f;       f += BB * MM;
    float* sRow = f;       f += BB * NN;
    float* sCol = f;       f += BB * MM;

    split_k<<<dim3(NN / 64, BB), 256, 0, stream>>>(src_emb, TA0, TA1, TA2, xx);
    split_k<<<dim3(MM / 64, BB), 256, 0, stream>>>(tgt_emb, TB0, TB1, TB2, yy);
    rstat_k<<<dim3(MM / 128, NN / 128, BB), 256, 0, stream>>>(TB0, TB1, TB2, TA0, TA1, TA2, yy,
                                                              rpM, rpS, rpI, rpM2, rpI2);
    comb_rowfix_k<<<dim3(NN / 256, BB), 256, 0, stream>>>(rpM, rpS, rpI, rpM2, rpI2,
                                                          src_emb, tgt_emb, yy, rpx, rinv, rowamax);
    cstat_scol_k<<<dim3(MM / 128, NN / 128, BB), 256, 0, stream>>>(TA0, TA1, TA2, TB0, TB1, TB2,
                                                                   xx, yy, rpx, rinv, cpM, cpS, sColp);
    comb_colscol_k<<<dim3(MM / 256, BB), 256, 0, stream>>>(cpM, cpS, sColp, dmx, cinv, sCol);
    srow_k<<<dim3(MM / 128, NN / 128, BB), 256, 0, stream>>>(TB0, TB1, TB2, TA0, TA1, TA2,
                                                             xx, dmx, cinv, sRowp);
    comb_srow_k<<<dim3(NN / 256, BB), 256, 0, stream>>>(sRowp, sRow);
    selmask_k<<<dim3(BB), 256, 0, stream>>>(sRow, sCol, out);
    pass3_k<<<dim3(MM / 128, NN / 128, BB), 256, 0, stream>>>(TA0, TA1, TB0, TB1, yy, rpx, rinv,
                                                              rowamax, out, tgt, csP, d0P, d1P, d2P);
    comb_corr_k<<<dim3(NN / 256, BB), 256, 0, stream>>>(csP, d0P, d1P, d2P, out);
}

// Round 8
// 296.382 us; speedup vs baseline: 1.4981x; 1.0764x over previous
//
#include <hip/hip_runtime.h>

// EPCOR eval path on MI355X — MFMA recompute, swizzled operands, 3 GEMM passes.
// pd never materialized. Row-argmax rescued exactly in fp32.
#define BB 8
#define CC 64
#define NN 2048
#define MM 2048
#define KSEL 613            // 0-based index of the 614-th smallest (int(2048*0.3)=614)
#define TSZ ((size_t)(2048 * 64))   // elements per batch per operand array

// Output layout (floats): src_corr [B,3,N] | src_weight [B,N] | mask_src [B,N] | mask_tgt [B,M]
#define OUT_W  (BB * 3 * NN)
#define OUT_MS (OUT_W + BB * NN)
#define OUT_MT (OUT_MS + BB * NN)

typedef unsigned short us;
typedef __attribute__((ext_vector_type(8))) short v8s;
typedef __attribute__((ext_vector_type(4))) float v4f;

static __device__ inline us f2bf(float x) {
    union { float f; unsigned u; } v; v.f = x;
    unsigned r = v.u + 0x7FFF + ((v.u >> 16) & 1);
    return (us)(r >> 16);
}
static __device__ inline float bf2f(us h) {
    union { float f; unsigned u; } v; v.u = ((unsigned)h) << 16; return v.f;
}

// ---------- split: fp32 [B,64,L] -> 3 swizzled bf16 operand arrays + sq-norms ----------
// swizzle: elem(n,c) at (n>>4)*1024 + (c>>5)*512 + ((c>>3)&3)*128 + (n&15)*8 + (c&7)
__global__ __launch_bounds__(256) void split_k(const float* __restrict__ inA,
                                               const float* __restrict__ inB,
                                               us* __restrict__ A0, us* __restrict__ A1,
                                               us* __restrict__ A2, float* __restrict__ nrmA,
                                               us* __restrict__ B0, us* __restrict__ B1,
                                               us* __restrict__ B2, float* __restrict__ nrmB) {
    __shared__ float tile[64][64];  // [c][n]
    __shared__ float xs[64][4];
    int b = blockIdx.y, n0 = blockIdx.x << 6, t = threadIdx.x;
    const float* in = blockIdx.z ? inB : inA;
    us* T0 = blockIdx.z ? B0 : A0;
    us* T1 = blockIdx.z ? B1 : A1;
    us* T2 = blockIdx.z ? B2 : A2;
    float* nrm = blockIdx.z ? nrmB : nrmA;
    int c4 = t >> 6, nl = t & 63;
#pragma unroll
    for (int r = 0; r < 16; ++r) {
        int c = (r << 2) + c4;
        tile[c][nl] = in[((size_t)(b * CC + c)) * NN + n0 + nl];
    }
    __syncthreads();
    int n = t >> 2, cq = t & 3;
    us h0[16], h1[16], h2[16];
    float ss = 0.f;
#pragma unroll
    for (int j = 0; j < 16; ++j) {
        float a = tile[cq * 16 + j][n];
        ss += a * a;
        h0[j] = f2bf(a);
        float r1 = a - bf2f(h0[j]);
        h1[j] = f2bf(r1);
        float r2 = r1 - bf2f(h1[j]);
        h2[j] = f2bf(r2);
    }
    xs[n][cq] = ss;
    size_t base = (size_t)b * TSZ + (size_t)((n0 + n) >> 4) * 1024
                + (size_t)(cq >> 1) * 512 + (size_t)((cq << 1) & 3) * 128 + (size_t)(n & 15) * 8;
    *(v8s*)(T0 + base) = *(v8s*)h0;       *(v8s*)(T0 + base + 128) = *(v8s*)(h0 + 8);
    *(v8s*)(T1 + base) = *(v8s*)h1;       *(v8s*)(T1 + base + 128) = *(v8s*)(h1 + 8);
    *(v8s*)(T2 + base) = *(v8s*)h2;       *(v8s*)(T2 + base + 128) = *(v8s*)(h2 + 8);
    __syncthreads();
    if (t < 64) nrm[b * NN + n0 + t] = xs[t][0] + xs[t][1] + xs[t][2] + xs[t][3];
}

// ---------- 6-term mainloop, swizzled coalesced fragment loads ----------
__device__ inline void gemm6(const us* __restrict__ A0, const us* __restrict__ A1,
                             const us* __restrict__ A2, const us* __restrict__ B0,
                             const us* __restrict__ B1, const us* __restrict__ B2,
                             int b, int n0, int m0, int l15, int quad, v4f acc[4][4]) {
    size_t bb = (size_t)b * TSZ;
#pragma unroll
    for (int ks = 0; ks < 2; ++ks) {
        size_t ra[4], rb[4];
#pragma unroll
        for (int q = 0; q < 4; ++q) {
            ra[q] = bb + (size_t)((n0 >> 4) + q) * 1024 + ks * 512 + quad * 128 + l15 * 8;
            rb[q] = bb + (size_t)((m0 >> 4) + q) * 1024 + ks * 512 + quad * 128 + l15 * 8;
        }
        v8s a0f[4], a1f[4], a2f[4], b0f[4], b1f[4], b2f[4];
#pragma unroll
        for (int q = 0; q < 4; ++q) { a0f[q] = *(const v8s*)(A0 + ra[q]); b0f[q] = *(const v8s*)(B0 + rb[q]); }
#pragma unroll
        for (int nt = 0; nt < 4; ++nt)
#pragma unroll
            for (int mt = 0; mt < 4; ++mt)
                acc[nt][mt] = __builtin_amdgcn_mfma_f32_16x16x32_bf16(a0f[nt], b0f[mt], acc[nt][mt], 0, 0, 0);
#pragma unroll
        for (int q = 0; q < 4; ++q) b1f[q] = *(const v8s*)(B1 + rb[q]);
#pragma unroll
        for (int nt = 0; nt < 4; ++nt)
#pragma unroll
            for (int mt = 0; mt < 4; ++mt)
                acc[nt][mt] = __builtin_amdgcn_mfma_f32_16x16x32_bf16(a0f[nt], b1f[mt], acc[nt][mt], 0, 0, 0);
#pragma unroll
        for (int q = 0; q < 4; ++q) b2f[q] = *(const v8s*)(B2 + rb[q]);
#pragma unroll
        for (int nt = 0; nt < 4; ++nt)
#pragma unroll
            for (int mt = 0; mt < 4; ++mt)
                acc[nt][mt] = __builtin_amdgcn_mfma_f32_16x16x32_bf16(a0f[nt], b2f[mt], acc[nt][mt], 0, 0, 0);
#pragma unroll
        for (int q = 0; q < 4; ++q) a1f[q] = *(const v8s*)(A1 + ra[q]);
#pragma unroll
        for (int nt = 0; nt < 4; ++nt)
#pragma unroll
            for (int mt = 0; mt < 4; ++mt)
                acc[nt][mt] = __builtin_amdgcn_mfma_f32_16x16x32_bf16(a1f[nt], b0f[mt], acc[nt][mt], 0, 0, 0);
#pragma unroll
        for (int nt = 0; nt < 4; ++nt)
#pragma unroll
            for (int mt = 0; mt < 4; ++mt)
                acc[nt][mt] = __builtin_amdgcn_mfma_f32_16x16x32_bf16(a1f[nt], b1f[mt], acc[nt][mt], 0, 0, 0);
#pragma unroll
        for (int q = 0; q < 4; ++q) a2f[q] = *(const v8s*)(A2 + ra[q]);
#pragma unroll
        for (int nt = 0; nt < 4; ++nt)
#pragma unroll
            for (int mt = 0; mt < 4; ++mt)
                acc[nt][mt] = __builtin_amdgcn_mfma_f32_16x16x32_bf16(a2f[nt], b0f[mt], acc[nt][mt], 0, 0, 0);
    }
}

// ---------- 3-term mainloop (corr): a0b0 + a0b1 + a1b0 ----------
__device__ inline void gemm3(const us* __restrict__ A0, const us* __restrict__ A1,
                             const us* __restrict__ B0, const us* __restrict__ B1,
                             int b, int n0, int m0, int l15, int quad, v4f acc[4][4]) {
    size_t bb = (size_t)b * TSZ;
#pragma unroll
    for (int ks = 0; ks < 2; ++ks) {
        size_t ra[4], rb[4];
#pragma unroll
        for (int q = 0; q < 4; ++q) {
            ra[q] = bb + (size_t)((n0 >> 4) + q) * 1024 + ks * 512 + quad * 128 + l15 * 8;
            rb[q] = bb + (size_t)((m0 >> 4) + q) * 1024 + ks * 512 + quad * 128 + l15 * 8;
        }
        v8s a0f[4], a1f[4], b0f[4], b1f[4];
#pragma unroll
        for (int q = 0; q < 4; ++q) { a0f[q] = *(const v8s*)(A0 + ra[q]); b0f[q] = *(const v8s*)(B0 + rb[q]); }
#pragma unroll
        for (int nt = 0; nt < 4; ++nt)
#pragma unroll
            for (int mt = 0; mt < 4; ++mt)
                acc[nt][mt] = __builtin_amdgcn_mfma_f32_16x16x32_bf16(a0f[nt], b0f[mt], acc[nt][mt], 0, 0, 0);
#pragma unroll
        for (int q = 0; q < 4; ++q) b1f[q] = *(const v8s*)(B1 + rb[q]);
#pragma unroll
        for (int nt = 0; nt < 4; ++nt)
#pragma unroll
            for (int mt = 0; mt < 4; ++mt)
                acc[nt][mt] = __builtin_amdgcn_mfma_f32_16x16x32_bf16(a0f[nt], b1f[mt], acc[nt][mt], 0, 0, 0);
#pragma unroll
        for (int q = 0; q < 4; ++q) a1f[q] = *(const v8s*)(A1 + ra[q]);
#pragma unroll
        for (int nt = 0; nt < 4; ++nt)
#pragma unroll
            for (int mt = 0; mt < 4; ++mt)
                acc[nt][mt] = __builtin_amdgcn_mfma_f32_16x16x32_bf16(a1f[nt], b0f[mt], acc[nt][mt], 0, 0, 0);
    }
}

#define IDS \
    int t = threadIdx.x; int lane = t & 63; int wave = t >> 6; \
    int wx = wave & 1, wy = wave >> 1; \
    int l15 = lane & 15, quad = lane >> 4; \
    int b = blockIdx.z;

// ---------- passA: SWAPPED gemm -> row top-2/sumexp (in-lane) AND col max/sumexp (l15 butterfly) ----------
// acc[it][jt]: m = m0+it*16+quad*4+r, n = n0+jt*16+l15.
__global__ __launch_bounds__(256, 2) void passA_k(const us* __restrict__ TB0, const us* __restrict__ TB1,
                                                  const us* __restrict__ TB2, const us* __restrict__ TA0,
                                                  const us* __restrict__ TA1, const us* __restrict__ TA2,
                                                  const float* __restrict__ xx,
                                                  const float* __restrict__ yy,
                                                  float* __restrict__ rpM, float* __restrict__ rpS,
                                                  int* __restrict__ rpI,
                                                  float* __restrict__ rpM2, int* __restrict__ rpI2,
                                                  float* __restrict__ cpM, float* __restrict__ cpS) {
    IDS
    int m0 = blockIdx.x * 128 + wx * 64;
    int n0 = blockIdx.y * 128 + wy * 64;
    v4f acc[4][4];
#pragma unroll
    for (int i = 0; i < 4; ++i)
#pragma unroll
        for (int j = 0; j < 4; ++j) acc[i][j] = (v4f){0.f, 0.f, 0.f, 0.f};
    gemm6(TB0, TB1, TB2, TA0, TA1, TA2, b, m0, n0, l15, quad, acc);
    // ---- col stats in shift space pd + yy[m] = 2acc - xx[n] ----
    float xv[4];
#pragma unroll
    for (int jt = 0; jt < 4; ++jt) xv[jt] = xx[b * NN + n0 + jt * 16 + l15];
    {
        float cmx[16], csm[16];
#pragma unroll
        for (int it = 0; it < 4; ++it)
#pragma unroll
            for (int r = 0; r < 4; ++r) {
                float cm = 2.f * acc[it][0][r] - xv[0];
#pragma unroll
                for (int jt = 1; jt < 4; ++jt)
                    cm = fmaxf(cm, 2.f * acc[it][jt][r] - xv[jt]);
                cmx[it * 4 + r] = cm;
            }
#pragma unroll
        for (int d = 1; d < 16; d <<= 1)
#pragma unroll
            for (int k = 0; k < 16; ++k) cmx[k] = fmaxf(cmx[k], __shfl_xor(cmx[k], d));
#pragma unroll
        for (int it = 0; it < 4; ++it)
#pragma unroll
            for (int r = 0; r < 4; ++r) {
                float s = 0.f;
#pragma unroll
                for (int jt = 0; jt < 4; ++jt)
                    s += __expf(2.f * acc[it][jt][r] - xv[jt] - cmx[it * 4 + r]);
                csm[it * 4 + r] = s;
            }
#pragma unroll
        for (int d = 1; d < 16; d <<= 1)
#pragma unroll
            for (int k = 0; k < 16; ++k) csm[k] += __shfl_xor(csm[k], d);
        if (l15 == 0) {
            size_t o = ((size_t)(b * 32 + 2 * blockIdx.y + wy)) * MM + m0 + quad * 4;
#pragma unroll
            for (int it = 0; it < 4; ++it) {
                *(float4*)&cpM[o + it * 16] = make_float4(cmx[it * 4], cmx[it * 4 + 1], cmx[it * 4 + 2], cmx[it * 4 + 3]);
                *(float4*)&cpS[o + it * 16] = make_float4(csm[it * 4], csm[it * 4 + 1], csm[it * 4 + 2], csm[it * 4 + 3]);
            }
        }
    }
    // ---- row top-2/sumexp in shift space pd + xx[n] = 2acc - yy[m] ----
    float ym[4][4];
#pragma unroll
    for (int it = 0; it < 4; ++it)
#pragma unroll
        for (int r = 0; r < 4; ++r) ym[it][r] = yy[b * MM + m0 + it * 16 + quad * 4 + r];
#pragma unroll
    for (int jt = 0; jt < 4; ++jt) {
        float w[16];
#pragma unroll
        for (int it = 0; it < 4; ++it)
#pragma unroll
            for (int r = 0; r < 4; ++r) w[it * 4 + r] = 2.f * acc[it][jt][r] - ym[it][r];
        float v1 = w[0]; int i1 = quad * 4;
        float v2 = -3.4e38f; int i2 = quad * 4;
#pragma unroll
        for (int k = 1; k < 16; ++k) {
            int ml = (k >> 2) * 16 + quad * 4 + (k & 3);
            if (w[k] > v1) { v2 = v1; i2 = i1; v1 = w[k]; i1 = ml; }
            else if (w[k] > v2) { v2 = w[k]; i2 = ml; }
        }
        float S = 0.f;
#pragma unroll
        for (int k = 0; k < 16; ++k) S += __expf(w[k] - v1);
#pragma unroll
        for (int d = 16; d <= 32; d <<= 1) {
            float oV1 = __shfl_xor(v1, d); float oS = __shfl_xor(S, d);
            int oi1 = __shfl_xor(i1, d);
            float oV2 = __shfl_xor(v2, d); int oi2 = __shfl_xor(i2, d);
            float nM = fmaxf(v1, oV1);
            S = S * __expf(v1 - nM) + oS * __expf(oV1 - nM);
            if (oV1 > v1) {
                if (v1 > oV2) { v2 = v1; i2 = i1; } else { v2 = oV2; i2 = oi2; }
                v1 = oV1; i1 = oi1;
            } else if (oV1 > v2) { v2 = oV1; i2 = oi1; }
        }
        if (quad == 0) {
            int n = n0 + jt * 16 + l15;
            size_t o = ((size_t)(b * 32 + 2 * blockIdx.x + wx)) * NN + n;
            rpM[o] = v1; rpS[o] = S; rpI[o] = m0 + i1; rpM2[o] = v2; rpI2[o] = m0 + i2;
        }
    }
}

// ---------- comb_rc: z=0 rows (merge top-2 + exact argmax rescue), z=1 cols ----------
__global__ __launch_bounds__(256) void comb_rc_k(const float* __restrict__ rpM,
                                                 const float* __restrict__ rpS,
                                                 const int* __restrict__ rpI,
                                                 const float* __restrict__ rpM2,
                                                 const int* __restrict__ rpI2,
                                                 const float* __restrict__ cpM,
                                                 const float* __restrict__ cpS,
                                                 const float* __restrict__ src_emb,
                                                 const float* __restrict__ tgt_emb,
                                                 const float* __restrict__ yy,
                                                 float* __restrict__ rpx, float* __restrict__ rinv,
                                                 int* __restrict__ rowamax,
                                                 float* __restrict__ dmx, float* __restrict__ cinv) {
    int b = blockIdx.y;
    int i = blockIdx.x * 256 + threadIdx.x;
    if (blockIdx.z == 1) {
        float M = -3.4e38f;
#pragma unroll
        for (int k = 0; k < 32; ++k) M = fmaxf(M, cpM[((size_t)(b * 32 + k)) * MM + i]);
        float S = 0.f;
#pragma unroll
        for (int k = 0; k < 32; ++k) {
            size_t o = ((size_t)(b * 32 + k)) * MM + i;
            S += cpS[o] * __expf(cpM[o] - M);
        }
        dmx[b * MM + i] = M;
        cinv[b * MM + i] = 1.f / S;
        return;
    }
    float V1 = -3.4e38f, V2 = -3.4e38f; int I1 = 0, I2 = 0;
#pragma unroll
    for (int k = 0; k < 32; ++k) {
        size_t o = ((size_t)(b * 32 + k)) * NN + i;
        float w1 = rpM[o], w2 = rpM2[o]; int j1 = rpI[o], j2 = rpI2[o];
        if (w1 > V1) {
            if (V1 > w2) { V2 = V1; I2 = I1; } else { V2 = w2; I2 = j2; }
            V1 = w1; I1 = j1;
        } else if (w1 > V2) { V2 = w1; I2 = j1; }
    }
    float S = 0.f;
#pragma unroll
    for (int k = 0; k < 32; ++k) {
        size_t o = ((size_t)(b * 32 + k)) * NN + i;
        S += rpS[o] * __expf(rpM[o] - V1);
    }
    rpx[b * NN + i] = V1;
    rinv[b * NN + i] = 1.f / S;
    const float* Sp = src_emb + (size_t)b * CC * NN;
    const float* Tp = tgt_emb + (size_t)b * CC * MM;
    float d1 = 0.f, d2 = 0.f;
#pragma unroll
    for (int c = 0; c < CC; ++c) {
        float s = Sp[(size_t)c * NN + i];
        d1 += s * Tp[(size_t)c * MM + I1];
        d2 += s * Tp[(size_t)c * MM + I2];
    }
    float p1 = 2.f * d1 - yy[b * MM + I1];
    float p2 = 2.f * d2 - yy[b * MM + I2];
    int best;
    if (p2 > p1) best = I2;
    else if (p1 > p2) best = I1;
    else best = (I1 < I2) ? I1 : I2;
    rowamax[b * NN + i] = best;
}

// ---------- passB: NORMAL gemm -> sCol (in-lane) AND sRow (l15 butterfly) partials ----------
// acc[nt][mt]: n = n0+nt*16+quad*4+r, m = m0+mt*16+l15.
__global__ __launch_bounds__(256, 3) void passB_k(const us* __restrict__ TA0, const us* __restrict__ TA1,
                                                  const us* __restrict__ TA2, const us* __restrict__ TB0,
                                                  const us* __restrict__ TB1, const us* __restrict__ TB2,
                                                  const float* __restrict__ xx,
                                                  const float* __restrict__ yy,
                                                  const float* __restrict__ rpx,
                                                  const float* __restrict__ rinv,
                                                  const float* __restrict__ dmx,
                                                  const float* __restrict__ cinv,
                                                  float* __restrict__ sRowp, float* __restrict__ sColp) {
    IDS
    int m0 = blockIdx.x * 128 + wx * 64;
    int n0 = blockIdx.y * 128 + wy * 64;
    v4f acc[4][4];
#pragma unroll
    for (int i = 0; i < 4; ++i)
#pragma unroll
        for (int j = 0; j < 4; ++j) acc[i][j] = (v4f){0.f, 0.f, 0.f, 0.f};
    gemm6(TA0, TA1, TA2, TB0, TB1, TB2, b, n0, m0, l15, quad, acc);
    // sCol[m] partial = sum_n exp(2acc - yy[m] - rpx[n]) * rinv[n]
    {
        float rpxv[4][4], rinvv[4][4];
#pragma unroll
        for (int nt = 0; nt < 4; ++nt)
#pragma unroll
            for (int r = 0; r < 4; ++r) {
                int n = n0 + nt * 16 + quad * 4 + r;
                rpxv[nt][r] = rpx[b * NN + n];
                rinvv[nt][r] = rinv[b * NN + n];
            }
#pragma unroll
        for (int mt = 0; mt < 4; ++mt) {
            float yv = yy[b * MM + m0 + mt * 16 + l15];
            float s = 0.f;
#pragma unroll
            for (int nt = 0; nt < 4; ++nt)
#pragma unroll
                for (int r = 0; r < 4; ++r)
                    s += __expf(2.f * acc[nt][mt][r] - yv - rpxv[nt][r]) * rinvv[nt][r];
            s += __shfl_xor(s, 16);
            s += __shfl_xor(s, 32);
            if (quad == 0)
                sColp[((size_t)(b * 32 + 2 * blockIdx.y + wy)) * MM + m0 + mt * 16 + l15] = s;
        }
    }
    // sRow[n] partial = sum_m exp(2acc - xx[n] - dmx[m]) * cinv[m]
    {
        float dm[4], ci[4];
#pragma unroll
        for (int mt = 0; mt < 4; ++mt) {
            int m = m0 + mt * 16 + l15;
            dm[mt] = dmx[b * MM + m];
            ci[mt] = cinv[b * MM + m];
        }
        float s[16];
#pragma unroll
        for (int nt = 0; nt < 4; ++nt)
#pragma unroll
            for (int r = 0; r < 4; ++r) {
                float xvv = xx[b * NN + n0 + nt * 16 + quad * 4 + r];
                float a = 0.f;
#pragma unroll
                for (int mt = 0; mt < 4; ++mt)
                    a += __expf(2.f * acc[nt][mt][r] - xvv - dm[mt]) * ci[mt];
                s[nt * 4 + r] = a;
            }
#pragma unroll
        for (int d = 1; d < 16; d <<= 1)
#pragma unroll
            for (int k = 0; k < 16; ++k) s[k] += __shfl_xor(s[k], d);
        if (l15 == 0) {
            size_t o = ((size_t)(b * 32 + 2 * blockIdx.x + wx)) * NN + n0 + quad * 4;
#pragma unroll
            for (int nt = 0; nt < 4; ++nt)
                *(float4*)&sRowp[o + nt * 16] = make_float4(s[nt * 4], s[nt * 4 + 1], s[nt * 4 + 2], s[nt * 4 + 3]);
        }
    }
}

// ---------- comb_s: sum partials. z=0 sRow, z=1 sCol ----------
__global__ __launch_bounds__(256) void comb_s_k(const float* __restrict__ sRowp,
                                                const float* __restrict__ sColp,
                                                float* __restrict__ sRow,
                                                float* __restrict__ sCol) {
    int b = blockIdx.y, which = blockIdx.z;
    int i = blockIdx.x * 256 + threadIdx.x;
    const float* p = which ? sColp : sRowp;
    float s = 0.f;
#pragma unroll
    for (int k = 0; k < 32; ++k) s += p[((size_t)(b * 32 + k)) * 2048 + i];
    (which ? sCol : sRow)[b * 2048 + i] = s;
}

// ---------- selmask: thresholds (614-th smallest) + masks + src_weight ----------
__global__ __launch_bounds__(256) void selmask_k(const float* __restrict__ sRow,
                                                 const float* __restrict__ sCol,
                                                 float* __restrict__ out) {
    __shared__ float th[2];
    __shared__ int wcnt[4];
    int b = blockIdx.x, t = threadIdx.x;
    int lane = t & 63, wv = t >> 6;
    if (wv < 2) {
        const float* vals = (wv == 0) ? (sRow + b * NN) : (sCol + b * MM);
        float v[32];
#pragma unroll
        for (int i = 0; i < 32; ++i) v[i] = vals[lane + (i << 6)];
        unsigned lo = 0u, hi = 0x7F800000u;
        while (lo < hi) {
            unsigned mid = lo + ((hi - lo) >> 1);
            float pv = __uint_as_float(mid);
            int c = 0;
#pragma unroll
            for (int i = 0; i < 32; ++i) c += (v[i] <= pv) ? 1 : 0;
#pragma unroll
            for (int off = 32; off > 0; off >>= 1) c += __shfl_down(c, off);
            c = __shfl(c, 0);
            if (c >= KSEL + 1) hi = mid; else lo = mid + 1;
        }
        if (lane == 0) th[wv] = __uint_as_float(lo);
    }
    __syncthreads();
    float r = th[0], c = th[1];
    int cnt = 0;
    bool ms[8];
#pragma unroll
    for (int i = 0; i < 8; ++i) {
        int n = t + (i << 8);
        ms[i] = sRow[b * NN + n] < r;
        out[OUT_MS + b * NN + n] = ms[i] ? 1.f : 0.f;
        out[OUT_MT + b * MM + n] = (sCol[b * MM + n] < c) ? 1.f : 0.f;
        cnt += ms[i] ? 0 : 1;
    }
#pragma unroll
    for (int off = 32; off > 0; off >>= 1) cnt += __shfl_down(cnt, off);
    if (lane == 0) wcnt[wv] = cnt;
    __syncthreads();
    float inv = 1.f / (float)(wcnt[0] + wcnt[1] + wcnt[2] + wcnt[3]);
#pragma unroll
    for (int i = 0; i < 8; ++i) {
        int n = t + (i << 8);
        out[OUT_W + b * NN + n] = ms[i] ? 0.f : inv;
    }
}

// ---------- passC: corr partials (3-term GEMM, normal orientation) ----------
__global__ __launch_bounds__(256, 3) void passC_k(const us* __restrict__ TA0, const us* __restrict__ TA1,
                                                  const us* __restrict__ TB0, const us* __restrict__ TB1,
                                                  const float* __restrict__ yy,
                                                  const float* __restrict__ rpx,
                                                  const float* __restrict__ rinv,
                                                  const int* __restrict__ rowamax,
                                                  const float* __restrict__ out,   // mask flags
                                                  const float* __restrict__ tgt,
                                                  float* __restrict__ csP, float* __restrict__ d0P,
                                                  float* __restrict__ d1P, float* __restrict__ d2P) {
    IDS
    int m0 = blockIdx.x * 128 + wx * 64;
    int n0 = blockIdx.y * 128 + wy * 64;
    v4f acc[4][4];
#pragma unroll
    for (int i = 0; i < 4; ++i)
#pragma unroll
        for (int j = 0; j < 4; ++j) acc[i][j] = (v4f){0.f, 0.f, 0.f, 0.f};
    gemm3(TA0, TA1, TB0, TB1, b, n0, m0, l15, quad, acc);
    float yv[4], t0[4], t1[4], t2[4]; bool mtgt[4]; int mg[4];
#pragma unroll
    for (int mt = 0; mt < 4; ++mt) {
        int m = m0 + mt * 16 + l15;
        mg[mt] = m;
        yv[mt] = yy[b * MM + m];
        mtgt[mt] = out[OUT_MT + b * MM + m] != 0.f;
        t0[mt] = tgt[((size_t)(b * 3 + 0)) * MM + m];
        t1[mt] = tgt[((size_t)(b * 3 + 1)) * MM + m];
        t2[mt] = tgt[((size_t)(b * 3 + 2)) * MM + m];
    }
#pragma unroll
    for (int nt = 0; nt < 4; ++nt) {
        float cs[4], e0[4], e1[4], e2[4];
#pragma unroll
        for (int r = 0; r < 4; ++r) {
            int n = n0 + nt * 16 + quad * 4 + r;
            float rpxn = rpx[b * NN + n];
            float rinn = rinv[b * NN + n];
            int kidx = rowamax[b * NN + n];
            bool ms = out[OUT_MS + b * NN + n] != 0.f;
            float a = 0.f, b0v = 0.f, b1v = 0.f, b2v = 0.f;
#pragma unroll
            for (int mt = 0; mt < 4; ++mt) {
                bool keep = ms || mtgt[mt] || (mg[mt] == kidx);
                if (keep) {
                    float s = __expf(2.f * acc[nt][mt][r] - yv[mt] - rpxn) * rinn;
                    a += s; b0v += s * t0[mt]; b1v += s * t1[mt]; b2v += s * t2[mt];
                }
            }
            cs[r] = a; e0[r] = b0v; e1[r] = b1v; e2[r] = b2v;
        }
#pragma unroll
        for (int d = 1; d < 16; d <<= 1)
#pragma unroll
            for (int r = 0; r < 4; ++r) {
                cs[r] += __shfl_xor(cs[r], d);
                e0[r] += __shfl_xor(e0[r], d);
                e1[r] += __shfl_xor(e1[r], d);
                e2[r] += __shfl_xor(e2[r], d);
            }
        if (l15 == 0) {
            size_t o = ((size_t)(b * 32 + 2 * blockIdx.x + wx)) * NN + n0 + nt * 16 + quad * 4;
            *(float4*)&csP[o] = make_float4(cs[0], cs[1], cs[2], cs[3]);
            *(float4*)&d0P[o] = make_float4(e0[0], e0[1], e0[2], e0[3]);
            *(float4*)&d1P[o] = make_float4(e1[0], e1[1], e1[2], e1[3]);
            *(float4*)&d2P[o] = make_float4(e2[0], e2[1], e2[2], e2[3]);
        }
    }
}

// ---------- comb_corr: combine corr partials -> src_corr ----------
__global__ __launch_bounds__(256) void comb_corr_k(const float* __restrict__ csP,
                                                   const float* __restrict__ d0P,
                                                   const float* __restrict__ d1P,
                                                   const float* __restrict__ d2P,
                                                   float* __restrict__ out) {
    int b = blockIdx.y;
    int n = blockIdx.x * 256 + threadIdx.x;
    float cs = 0.f, e0 = 0.f, e1 = 0.f, e2 = 0.f;
#pragma unroll
    for (int k = 0; k < 32; ++k) {
        size_t o = ((size_t)(b * 32 + k)) * NN + n;
        cs += csP[o]; e0 += d0P[o]; e1 += d1P[o]; e2 += d2P[o];
    }
    cs = (cs < 1e-5f) ? 1e-5f : cs;
    out[((size_t)(b * 3 + 0)) * NN + n] = e0 / cs;
    out[((size_t)(b * 3 + 1)) * NN + n] = e1 / cs;
    out[((size_t)(b * 3 + 2)) * NN + n] = e2 / cs;
}

extern "C" void kernel_launch(void* const* d_in, const int* in_sizes, int n_in,
                              void* d_out, int out_size, void* d_ws, size_t ws_size,
                              hipStream_t stream) {
    const float* src_emb = (const float*)d_in[0];
    const float* tgt_emb = (const float*)d_in[1];
    const float* tgt = (const float*)d_in[3];
    float* out = (float*)d_out;

    us* u = (us*)d_ws;
    us* TA0 = u;              us* TA1 = TA0 + BB * TSZ; us* TA2 = TA1 + BB * TSZ;
    us* TB0 = TA2 + BB * TSZ; us* TB1 = TB0 + BB * TSZ; us* TB2 = TB1 + BB * TSZ;
    float* f = (float*)(TB2 + BB * TSZ);
    const size_t P = (size_t)BB * 32 * NN;
    float* rpM = f;        f += P;
    float* rpS = f;        f += P;
    int*   rpI = (int*)f;  f += P;
    float* rpM2 = f;       f += P;
    int*   rpI2 = (int*)f; f += P;
    float* cpM = f;        f += P;
    float* cpS = f;        f += P;
    float* sColp = f;      f += P;
    float* sRowp = f;      f += P;
    float* csP = f;        f += P;
    float* d0P = f;        f += P;
    float* d1P = f;        f += P;
    float* d2P = f;        f += P;
    float* xx = f;         f += BB * NN;
    float* yy = f;         f += BB * MM;
    float* rpx = f;        f += BB * NN;
    float* rinv = f;       f += BB * NN;
    int*   rowamax = (int*)f; f += BB * NN;
    float* dmx = f;        f += BB * MM;
    float* cinv = f;       f += BB * MM;
    float* sRow = f;       f += BB * NN;
    float* sCol = f;       f += BB * MM;

    split_k<<<dim3(NN / 64, BB, 2), 256, 0, stream>>>(src_emb, tgt_emb,
                                                      TA0, TA1, TA2, xx, TB0, TB1, TB2, yy);
    passA_k<<<dim3(MM / 128, NN / 128, BB), 256, 0, stream>>>(TB0, TB1, TB2, TA0, TA1, TA2,
                                                              xx, yy, rpM, rpS, rpI, rpM2, rpI2,
                                                              cpM, cpS);
    comb_rc_k<<<dim3(2048 / 256, BB, 2), 256, 0, stream>>>(rpM, rpS, rpI, rpM2, rpI2, cpM, cpS,
                                                           src_emb, tgt_emb, yy,
                                                           rpx, rinv, rowamax, dmx, cinv);
    passB_k<<<dim3(MM / 128, NN / 128, BB), 256, 0, stream>>>(TA0, TA1, TA2, TB0, TB1, TB2,
                                                              xx, yy, rpx, rinv, dmx, cinv,
                                                              sRowp, sColp);
    comb_s_k<<<dim3(2048 / 256, BB, 2), 256, 0, stream>>>(sRowp, sColp, sRow, sCol);
    selmask_k<<<dim3(BB), 256, 0, stream>>>(sRow, sCol, out);
    passC_k<<<dim3(MM / 128, NN / 128, BB), 256, 0, stream>>>(TA0, TA1, TB0, TB1, yy, rpx, rinv,
                                                              rowamax, out, tgt, csP, d0P, d1P, d2P);
    comb_corr_k<<<dim3(NN / 256, BB), 256, 0, stream>>>(csP, d0P, d1P, d2P, out);
}